// Round 6
// baseline (344.913 us; speedup 1.0000x reference)
//
#include <hip/hip_runtime.h>

#define EMBED 1024
#define HID   4096
#define NB    4
#define SEQ   2048

typedef __attribute__((ext_vector_type(8)))  __bf16 bf16x8;
typedef __attribute__((ext_vector_type(4)))  float  f32x4;
typedef __attribute__((ext_vector_type(16))) float  f32x16;
typedef __attribute__((ext_vector_type(4)))  int    i32x4;
typedef unsigned short u16;

__device__ __forceinline__ u16 f2bf(float f) {
  unsigned u = __float_as_uint(f);
  u += 0x7FFFu + ((u >> 16) & 1u);
  return (u16)(u >> 16);
}

typedef const __attribute__((address_space(1))) unsigned int* gas_t;
typedef __attribute__((address_space(3))) unsigned int* las_t;
__device__ __forceinline__ void gld16(const void* g, void* l) {
  __builtin_amdgcn_global_load_lds((gas_t)g, (las_t)l, 16, 0, 0);
}

#define RD16(p)       __builtin_bit_cast(bf16x8, *(const i32x4*)(p))
#define MFMA16(a,b,c) __builtin_amdgcn_mfma_f32_16x16x32_bf16(a, b, c, 0, 0, 0)
#define MFMA32(a,b,c) __builtin_amdgcn_mfma_f32_32x32x16_bf16(a, b, c, 0, 0, 0)
#define SCHED0()      __builtin_amdgcn_sched_barrier(0)
#define BARR()        __builtin_amdgcn_s_barrier()
#define LGKM(n)       asm volatile("s_waitcnt lgkmcnt(" #n ")" ::: "memory")
#define VMW(n)        asm volatile("s_waitcnt vmcnt(" #n ")" ::: "memory")

// ---------------------------------------------------------------------------
// 256x256 NT GEMM v2: 32x32x16 MFMA, single trailing barrier per phase.
// BK=64, 512 thr (8 waves 2Mx4N; per-wave 128x64 = 4 mfrag x 2 nfrag of 32).
// 2 LDS buffers (128KB). A rows stored REGION-REORDERED: LDS row' =
// p*64 + half*32 + rr for global row = half*128 + p*32 + rr, so phase-p's
// A rows form one contiguous 8KB region (one gld16 unit). Region p is read
// ONLY in phase p -> freed at barrier p. Stage ledger identical to the
// proven round-3/5 one (8 x 8KB units/K-tile, VMW(6) at ph3).
// EPI: 0 bias->bf16 | 1 *scale->f32 | 3 bias,relu->bf16
// ---------------------------------------------------------------------------
template<int EPI>
__global__ __launch_bounds__(512, 2) void gemm256v2(
    const u16* __restrict__ A, int lda, long long astr,
    const u16* __restrict__ B, int ldb, long long bstr,
    void* __restrict__ C, int ldc, long long cstr,
    const float* __restrict__ bias,
    float scale, int Kdim)
{
  __shared__ char lds[131072];   // buf b: A at b*65536 (reordered), B at +32768

  const int tid  = threadIdx.x;
  const int lane = tid & 63;
  const int w    = tid >> 6;
  const int wr   = w >> 2, wc = w & 3;    // 2x4 waves -> per-wave 128x64
  const int l31  = lane & 31, l5 = lane >> 5;

  // XCD swizzle (per-z-slice grids all have nwg%8==0)
  const int gx   = gridDim.x;
  const int nwg  = gx * gridDim.y;
  const int orig = blockIdx.y * gx + blockIdx.x;
  const int t    = ((nwg & 7) == 0) ? ((orig & 7) * (nwg >> 3) + (orig >> 3)) : orig;
  const int bx   = t % gx, by = t / gx;

  const u16* Ab = A + (size_t)blockIdx.z * astr + (size_t)by * 256 * lda;
  const u16* Bb = B + (size_t)blockIdx.z * bstr + (size_t)bx * 256 * ldb;

  // staging: 8KB per issue (512 thr x 16B), linear LDS dest, pre-swizzled src
  const int schunk = (tid & 7) ^ ((tid >> 3) & 7);
  auto stA = [&](int buf, int p, int kk) {   // A region p (reordered rows)
    const int grow = ((tid >> 8) << 7) + p * 32 + ((tid >> 3) & 31);
    gld16(Ab + (size_t)grow * lda + kk + schunk * 8,
          lds + buf * 65536 + p * 8192 + tid * 16);
  };
  auto stB = [&](int buf, int u, int kk) {   // B rows u*64..+64 (natural)
    const int grow = u * 64 + (tid >> 3);
    gld16(Bb + (size_t)grow * ldb + kk + schunk * 8,
          lds + buf * 65536 + 32768 + u * 8192 + tid * 16);
  };

  // LDS read offsets. A frag (phase mf): row' = mf*64 + wr*32 + l31.
  // B frag nf: row = wc*64 + nf*32 + l31. chunk = (ks*2+l5) XOR (row&7).
  const int arow = (wr * 32 + l31) * 128;            // + mf*8192
  const int brow = 32768 + (wc * 64 + l31) * 128;    // + nf*4096
  const int cs0 = ((0 + l5) ^ (lane & 7)) * 16;
  const int cs1 = ((2 + l5) ^ (lane & 7)) * 16;
  const int cs2 = ((4 + l5) ^ (lane & 7)) * 16;
  const int cs3 = ((6 + l5) ^ (lane & 7)) * 16;

  f32x16 acc[4][2] = {};
  bf16x8 bf[2][4];

#define BR32(LB) \
    bf[0][0] = RD16((LB) + brow + cs0); \
    bf[0][1] = RD16((LB) + brow + cs1); \
    bf[0][2] = RD16((LB) + brow + cs2); \
    bf[0][3] = RD16((LB) + brow + cs3); \
    bf[1][0] = RD16((LB) + brow + 4096 + cs0); \
    bf[1][1] = RD16((LB) + brow + 4096 + cs1); \
    bf[1][2] = RD16((LB) + brow + 4096 + cs2); \
    bf[1][3] = RD16((LB) + brow + 4096 + cs3);

#define PH32(LB, MF, STG, VMST) do { \
    bf16x8 a0 = RD16((LB) + (MF) * 8192 + arow + cs0); \
    bf16x8 a1 = RD16((LB) + (MF) * 8192 + arow + cs1); \
    bf16x8 a2 = RD16((LB) + (MF) * 8192 + arow + cs2); \
    bf16x8 a3 = RD16((LB) + (MF) * 8192 + arow + cs3); \
    STG VMST \
    LGKM(0); SCHED0(); \
    __builtin_amdgcn_s_setprio(1); \
    acc[MF][0] = MFMA32(a0, bf[0][0], acc[MF][0]); \
    acc[MF][1] = MFMA32(a0, bf[1][0], acc[MF][1]); \
    acc[MF][0] = MFMA32(a1, bf[0][1], acc[MF][0]); \
    acc[MF][1] = MFMA32(a1, bf[1][1], acc[MF][1]); \
    acc[MF][0] = MFMA32(a2, bf[0][2], acc[MF][0]); \
    acc[MF][1] = MFMA32(a2, bf[1][2], acc[MF][1]); \
    acc[MF][0] = MFMA32(a3, bf[0][3], acc[MF][0]); \
    acc[MF][1] = MFMA32(a3, bf[1][3], acc[MF][1]); \
    __builtin_amdgcn_s_setprio(0); \
    SCHED0(); BARR(); \
  } while (0)

  const int NT = Kdim >> 6;
  const int NI = NT >> 1;
  const char* L0 = lds;
  const char* L1 = lds + 65536;

  // prologue: tile0 (8 oldest units) + tile1 B + A regions 0,2
  stB(0, 0, 0); stB(0, 1, 0); stB(0, 2, 0); stB(0, 3, 0);
  stA(0, 0, 0); stA(0, 1, 0); stA(0, 2, 0); stA(0, 3, 0);
  stB(1, 0, 64); stB(1, 1, 64); stB(1, 2, 64); stB(1, 3, 64);
  stA(1, 0, 64); stA(1, 2, 64);
  VMW(6);                       // retire 8 oldest = tile0 landed
  BARR(); SCHED0();

  for (int I = 0; I < NI; ++I) {
    const bool st = (I + 1 < NI);
    const int k1 = (2 * I + 1) * 64;
    const int k2 = (2 * I + 2) * 64;
    const int k3 = (2 * I + 3) * 64;

    // ---- K-tile 2I (buf0) ----
    PH32(L0, 0, BR32(L0) { stA(1, 1, k1); stA(1, 3, k1); }, ;);
    PH32(L0, 1, if (st) { stB(0, 0, k2); stB(0, 1, k2); }, ;);
    PH32(L0, 2, if (st) { stB(0, 2, k2); stB(0, 3, k2); }, ;);
    if (st) { PH32(L0, 3, { stA(0, 0, k2); stA(0, 2, k2); }, VMW(6);); }
    else    { PH32(L0, 3, ;, VMW(0);); }
    // ---- K-tile 2I+1 (buf1) ----
    PH32(L1, 0, BR32(L1) if (st) { stA(0, 1, k2); stA(0, 3, k2); }, ;);
    PH32(L1, 1, if (st) { stB(1, 0, k3); stB(1, 1, k3); }, ;);
    PH32(L1, 2, if (st) { stB(1, 2, k3); stB(1, 3, k3); }, ;);
    if (st) { PH32(L1, 3, { stA(1, 0, k3); stA(1, 2, k3); }, VMW(6);); }
    else    { PH32(L1, 3, ;, ;); }
  }
#undef PH32
#undef BR32

  // epilogue: 32x32 C/D layout (m74/m101): col=lane&31,
  // row = (reg&3) + 8*(reg>>2) + 4*(lane>>5)
  const int bm0 = by * 256 + wr * 128;
  const int bn0 = bx * 256 + wc * 64;
  const size_t zoff = (size_t)blockIdx.z * cstr;
  float* Cf = (float*)C;
  u16*   Ch = (u16*)C;

#define ST32(MF, NF) do { \
    const int col = bn0 + (NF) * 32 + l31; \
    const int rb  = bm0 + (MF) * 32 + l5 * 4; \
    float bv = 0.f; \
    if (EPI == 0 || EPI == 3) bv = bias[col]; \
    _Pragma("unroll") \
    for (int r = 0; r < 16; ++r) { \
      const int row = rb + (r & 3) + ((r >> 2) << 3); \
      const size_t idx = zoff + (size_t)row * ldc + col; \
      const float v = acc[MF][NF][r]; \
      if      (EPI == 0) Ch[idx] = f2bf(v + bv); \
      else if (EPI == 1) Cf[idx] = v * scale; \
      else if (EPI == 3) Ch[idx] = f2bf(fmaxf(v + bv, 0.f)); \
    } \
  } while (0)

  ST32(0, 0); ST32(0, 1); ST32(1, 0); ST32(1, 1);
  ST32(2, 0); ST32(2, 1); ST32(3, 0); ST32(3, 1);
#undef ST32
}

// ---------------------------------------------------------------------------
// Deep-pipelined 256x128 NT GEMM; inner barriers removed (one barrier/tile).
// 3-slot LDS ledger: stages target slot s+2, reads slot s; the tile-top
// VMW(6)+BARR publishes all waves' DMA before any read.
// EPI: 0 col-bias->bf16 | 1 *scale->f32 | 2 +add->f32 | 4 col-bias,+add->f32
//      5 row-bias->bf16 (direct V^T projection)
// ---------------------------------------------------------------------------
template<int EPI>
__global__ __launch_bounds__(512, 2) void gemm8p(
    const u16* __restrict__ A, int lda, long long astr,
    const u16* __restrict__ B, int ldb, long long bstr,
    void* __restrict__ C, int ldc, long long cstr,
    const float* __restrict__ bias,
    const float* __restrict__ add,
    float scale, int Kdim)
{
  __shared__ i32x4 lds4[9216];           // 3 slots x 48KB (A 32KB + B 16KB)
  const int SLOT = 49152;

  const int tid  = threadIdx.x;
  const int lane = tid & 63;
  const int w    = tid >> 6;
  const int wr   = w >> 1, wc = w & 1;
  const int l15  = lane & 15, l4 = lane >> 4;

  const int gx   = gridDim.x;
  const int nwg  = gx * gridDim.y;
  const int orig = blockIdx.y * gx + blockIdx.x;
  const int t    = ((nwg & 7) == 0) ? ((orig & 7) * (nwg >> 3) + (orig >> 3)) : orig;
  const int bx   = t % gx, by = t / gx;

  const u16* Ab = A + (size_t)blockIdx.z * astr + (size_t)by * 256 * lda;
  const u16* Bb = B + (size_t)blockIdx.z * bstr + (size_t)bx * 128 * ldb;

  size_t gaoff[4], gboff[2];
  #pragma unroll
  for (int i = 0; i < 4; ++i) {
    const int idx = i * 512 + tid, row = idx >> 3, gc = (idx & 7) ^ (row & 7);
    gaoff[i] = (size_t)row * lda + gc * 8;
  }
  #pragma unroll
  for (int j = 0; j < 2; ++j) {
    const int idx = j * 512 + tid, row = idx >> 3, gc = (idx & 7) ^ (row & 7);
    gboff[j] = (size_t)row * ldb + gc * 8;
  }

  int aoff[4], boff[4], cp16[2];
  #pragma unroll
  for (int m = 0; m < 4; ++m) aoff[m] = (wr * 64 + m * 16 + l15) * 128;
  #pragma unroll
  for (int n = 0; n < 4; ++n) boff[n] = 32768 + (wc * 64 + n * 16 + l15) * 128;
  cp16[0] = ((0 + l4) ^ (l15 & 7)) * 16;
  cp16[1] = ((4 + l4) ^ (l15 & 7)) * 16;

  f32x4 acc[4][4] = {};
  const int NT = Kdim >> 6;
  char* lbase = (char*)lds4;

  {
    char* s0 = lbase;
    char* s1 = lbase + SLOT;
    #pragma unroll
    for (int i = 0; i < 4; ++i) gld16(Ab + gaoff[i],      s0 + (i * 512 + w * 64) * 16);
    #pragma unroll
    for (int j = 0; j < 2; ++j) gld16(Bb + gboff[j],      s0 + 32768 + (j * 512 + w * 64) * 16);
    #pragma unroll
    for (int i = 0; i < 4; ++i) gld16(Ab + gaoff[i] + 64, s1 + (i * 512 + w * 64) * 16);
    #pragma unroll
    for (int j = 0; j < 2; ++j) gld16(Bb + gboff[j] + 64, s1 + 32768 + (j * 512 + w * 64) * 16);
  }

  int s = 0;
  for (int T = 0; T < NT; ++T) {
    const bool st  = (T + 2 < NT);
    const size_t kk = (size_t)(T + 2) * 64;
    const char* rA = lbase + s * SLOT;
    char* wS = lbase + ((s + 2 >= 3) ? (s - 1) : (s + 2)) * SLOT;

    if (T == NT - 1) VMW(0);
    else             VMW(6);
    BARR();
    SCHED0();

    bf16x8 b0, b1, b2, b3, a0, a1;

    b0 = RD16(rA + boff[0] + cp16[0]);
    b1 = RD16(rA + boff[1] + cp16[0]);
    b2 = RD16(rA + boff[2] + cp16[0]);
    b3 = RD16(rA + boff[3] + cp16[0]);
    a0 = RD16(rA + aoff[0] + cp16[0]);
    a1 = RD16(rA + aoff[1] + cp16[0]);
    if (st) {
      gld16(Ab + gaoff[0] + kk, wS + (0 * 512 + w * 64) * 16);
      gld16(Ab + gaoff[1] + kk, wS + (1 * 512 + w * 64) * 16);
    }
    LGKM(0);
    SCHED0();
    __builtin_amdgcn_s_setprio(1);
    acc[0][0] = MFMA16(a0, b0, acc[0][0]);
    acc[0][1] = MFMA16(a0, b1, acc[0][1]);
    acc[0][2] = MFMA16(a0, b2, acc[0][2]);
    acc[0][3] = MFMA16(a0, b3, acc[0][3]);
    acc[1][0] = MFMA16(a1, b0, acc[1][0]);
    acc[1][1] = MFMA16(a1, b1, acc[1][1]);
    acc[1][2] = MFMA16(a1, b2, acc[1][2]);
    acc[1][3] = MFMA16(a1, b3, acc[1][3]);
    __builtin_amdgcn_s_setprio(0);

    a0 = RD16(rA + aoff[2] + cp16[0]);
    a1 = RD16(rA + aoff[3] + cp16[0]);
    if (st) {
      gld16(Ab + gaoff[2] + kk, wS + (2 * 512 + w * 64) * 16);
      gld16(Ab + gaoff[3] + kk, wS + (3 * 512 + w * 64) * 16);
    }
    LGKM(0);
    SCHED0();
    __builtin_amdgcn_s_setprio(1);
    acc[2][0] = MFMA16(a0, b0, acc[2][0]);
    acc[2][1] = MFMA16(a0, b1, acc[2][1]);
    acc[2][2] = MFMA16(a0, b2, acc[2][2]);
    acc[2][3] = MFMA16(a0, b3, acc[2][3]);
    acc[3][0] = MFMA16(a1, b0, acc[3][0]);
    acc[3][1] = MFMA16(a1, b1, acc[3][1]);
    acc[3][2] = MFMA16(a1, b2, acc[3][2]);
    acc[3][3] = MFMA16(a1, b3, acc[3][3]);
    __builtin_amdgcn_s_setprio(0);

    b0 = RD16(rA + boff[0] + cp16[1]);
    b1 = RD16(rA + boff[1] + cp16[1]);
    b2 = RD16(rA + boff[2] + cp16[1]);
    b3 = RD16(rA + boff[3] + cp16[1]);
    a0 = RD16(rA + aoff[0] + cp16[1]);
    a1 = RD16(rA + aoff[1] + cp16[1]);
    if (st) {
      gld16(Bb + gboff[0] + kk, wS + 32768 + (0 * 512 + w * 64) * 16);
    }
    LGKM(0);
    SCHED0();
    __builtin_amdgcn_s_setprio(1);
    acc[0][0] = MFMA16(a0, b0, acc[0][0]);
    acc[0][1] = MFMA16(a0, b1, acc[0][1]);
    acc[0][2] = MFMA16(a0, b2, acc[0][2]);
    acc[0][3] = MFMA16(a0, b3, acc[0][3]);
    acc[1][0] = MFMA16(a1, b0, acc[1][0]);
    acc[1][1] = MFMA16(a1, b1, acc[1][1]);
    acc[1][2] = MFMA16(a1, b2, acc[1][2]);
    acc[1][3] = MFMA16(a1, b3, acc[1][3]);
    __builtin_amdgcn_s_setprio(0);

    a0 = RD16(rA + aoff[2] + cp16[1]);
    a1 = RD16(rA + aoff[3] + cp16[1]);
    if (st) {
      gld16(Bb + gboff[1] + kk, wS + 32768 + (1 * 512 + w * 64) * 16);
    }
    LGKM(0);
    SCHED0();
    __builtin_amdgcn_s_setprio(1);
    acc[2][0] = MFMA16(a0, b0, acc[2][0]);
    acc[2][1] = MFMA16(a0, b1, acc[2][1]);
    acc[2][2] = MFMA16(a0, b2, acc[2][2]);
    acc[2][3] = MFMA16(a0, b3, acc[2][3]);
    acc[3][0] = MFMA16(a1, b0, acc[3][0]);
    acc[3][1] = MFMA16(a1, b1, acc[3][1]);
    acc[3][2] = MFMA16(a1, b2, acc[3][2]);
    acc[3][3] = MFMA16(a1, b3, acc[3][3]);
    __builtin_amdgcn_s_setprio(0);

    s = (s + 1 == 3) ? 0 : s + 1;
  }

  const int bm0 = by * 256 + wr * 64;
  const int bn0 = bx * 128 + wc * 64;
  float* Cf = (float*)C;
  u16*   Ch = (u16*)C;
  #pragma unroll
  for (int mi = 0; mi < 4; ++mi) {
    #pragma unroll
    for (int ni = 0; ni < 4; ++ni) {
      const int col = bn0 + ni * 16 + l15;
      const int r0  = bm0 + mi * 16 + l4 * 4;
      float bv = 0.f;
      if (EPI == 0 || EPI == 4) bv = bias[col];
      #pragma unroll
      for (int r = 0; r < 4; ++r) {
        const size_t idx = (size_t)blockIdx.z * cstr + (size_t)(r0 + r) * ldc + col;
        const float v = acc[mi][ni][r];
        if      (EPI == 0) Ch[idx] = f2bf(v + bv);
        else if (EPI == 1) Cf[idx] = v * scale;
        else if (EPI == 2) Cf[idx] = v + add[idx];
        else if (EPI == 4) Cf[idx] = v + bv + add[idx];
        else if (EPI == 5) Ch[idx] = f2bf(v + bias[r0 + r]);
      }
    }
  }
}

// ---------------------------------------------------------------------------
__global__ __launch_bounds__(256) void ln_kernel(
    const float* __restrict__ x, const float* __restrict__ g,
    const float* __restrict__ be, u16* __restrict__ out)
{
  const int row = blockIdx.x;
  const int tid = threadIdx.x;
  const float4 v = ((const float4*)(x + (size_t)row * EMBED))[tid];
  float s  = v.x + v.y + v.z + v.w;
  float s2 = v.x * v.x + v.y * v.y + v.z * v.z + v.w * v.w;
  #pragma unroll
  for (int m = 1; m < 64; m <<= 1) { s += __shfl_xor(s, m); s2 += __shfl_xor(s2, m); }
  __shared__ float ls[4], ls2[4];
  const int w = tid >> 6;
  if ((tid & 63) == 0) { ls[w] = s; ls2[w] = s2; }
  __syncthreads();
  s  = ls[0] + ls[1] + ls[2] + ls[3];
  s2 = ls2[0] + ls2[1] + ls2[2] + ls2[3];
  const float mu   = s * (1.f / EMBED);
  const float var  = s2 * (1.f / EMBED) - mu * mu;
  const float rstd = rsqrtf(var + 1e-5f);
  const float4 gv = ((const float4*)g)[tid];
  const float4 bv = ((const float4*)be)[tid];
  ushort4 o;
  o.x = f2bf((v.x - mu) * rstd * gv.x + bv.x);
  o.y = f2bf((v.y - mu) * rstd * gv.y + bv.y);
  o.z = f2bf((v.z - mu) * rstd * gv.z + bv.z);
  o.w = f2bf((v.w - mu) * rstd * gv.w + bv.w);
  ((ushort4*)(out + (size_t)row * EMBED))[tid] = o;
}

// ---------------------------------------------------------------------------
__global__ __launch_bounds__(256) void softmax_kernel(
    const float* __restrict__ S, u16* __restrict__ P)
{
  const int tid = threadIdx.x;
  const size_t base = ((size_t)blockIdx.y * SEQ + blockIdx.x) * SEQ;
  const float4* src = (const float4*)(S + base);
  float4 a = src[tid];
  float4 b = src[tid + 256];
  float m = fmaxf(fmaxf(fmaxf(a.x, a.y), fmaxf(a.z, a.w)),
                  fmaxf(fmaxf(b.x, b.y), fmaxf(b.z, b.w)));
  #pragma unroll
  for (int msk = 1; msk < 64; msk <<= 1) m = fmaxf(m, __shfl_xor(m, msk));
  __shared__ float red[8];
  const int w = tid >> 6;
  if ((tid & 63) == 0) red[w] = m;
  __syncthreads();
  m = fmaxf(fmaxf(red[0], red[1]), fmaxf(red[2], red[3]));
  a.x = __expf(a.x - m); a.y = __expf(a.y - m); a.z = __expf(a.z - m); a.w = __expf(a.w - m);
  b.x = __expf(b.x - m); b.y = __expf(b.y - m); b.z = __expf(b.z - m); b.w = __expf(b.w - m);
  float s = a.x + a.y + a.z + a.w + b.x + b.y + b.z + b.w;
  #pragma unroll
  for (int msk = 1; msk < 64; msk <<= 1) s += __shfl_xor(s, msk);
  if ((tid & 63) == 0) red[4 + w] = s;
  __syncthreads();
  s = red[4] + red[5] + red[6] + red[7];
  const float inv = 1.0f / s;
  ushort4 oa, ob;
  oa.x = f2bf(a.x * inv); oa.y = f2bf(a.y * inv); oa.z = f2bf(a.z * inv); oa.w = f2bf(a.w * inv);
  ob.x = f2bf(b.x * inv); ob.y = f2bf(b.y * inv); ob.z = f2bf(b.z * inv); ob.w = f2bf(b.w * inv);
  ushort4* dst = (ushort4*)(P + base);
  dst[tid]       = oa;
  dst[tid + 256] = ob;
}

// ---------------------------------------------------------------------------
__global__ void transpose_cast_f32(const float* __restrict__ W, u16* __restrict__ Wt,
                                   int K, int N)
{
  __shared__ float t[32][33];
  const int tx = threadIdx.x, ty = threadIdx.y;
  const int n0 = blockIdx.x * 32, k0 = blockIdx.y * 32;
  #pragma unroll
  for (int i = 0; i < 4; ++i)
    t[ty + i * 8][tx] = W[(size_t)(k0 + ty + i * 8) * N + n0 + tx];
  __syncthreads();
  #pragma unroll
  for (int i = 0; i < 4; ++i)
    Wt[(size_t)(n0 + ty + i * 8) * K + k0 + tx] = f2bf(t[tx][ty + i * 8]);
}

__global__ void concat_bias2(const float* __restrict__ a, const float* __restrict__ b,
                             float* __restrict__ o)
{
  const int i = blockIdx.x * 1024 + threadIdx.x;
  o[i] = (i < 1024) ? a[i] : b[i - 1024];
}

// ---------------------------------------------------------------------------
extern "C" void kernel_launch(void* const* d_in, const int* in_sizes, int n_in,
                              void* d_out, int out_size, void* d_ws, size_t ws_size,
                              hipStream_t stream)
{
  const float* x   = (const float*)d_in[0];
  const float* Wq  = (const float*)d_in[1];
  const float* bq  = (const float*)d_in[2];
  const float* Wk  = (const float*)d_in[3];
  const float* bk  = (const float*)d_in[4];
  const float* Wv  = (const float*)d_in[5];
  const float* bv  = (const float*)d_in[6];
  const float* W1  = (const float*)d_in[7];
  const float* b1  = (const float*)d_in[8];
  const float* W2  = (const float*)d_in[9];
  const float* b2  = (const float*)d_in[10];
  const float* g1  = (const float*)d_in[11];
  const float* be1 = (const float*)d_in[12];
  const float* g2  = (const float*)d_in[13];
  const float* be2 = (const float*)d_in[14];
  float* out = (float*)d_out;

  const size_t RD = (size_t)NB * SEQ * EMBED;

  char* base = (char*)d_ws;
  size_t o = 0;
  auto alloc = [&](size_t bytes) -> void* {
    o = (o + 255) & ~(size_t)255;
    void* p = base + o;
    o += bytes;
    return p;
  };

  u16*   wqkT = (u16*)alloc((size_t)2 * EMBED * EMBED * 2);   // [2048][1024]
  u16*   wvT  = (u16*)alloc((size_t)EMBED * EMBED * 2);       // [1024][1024]
  u16*   w1T  = (u16*)alloc((size_t)HID * EMBED * 2);         // [4096][1024]
  u16*   w2T  = (u16*)alloc((size_t)EMBED * HID * 2);         // [1024][4096]
  float* bqk  = (float*)alloc(2048 * 4);
  u16*   h    = (u16*)alloc(RD * 2);
  u16*   QKb  = (u16*)alloc(RD * 2 * 2);                      // [8192][2048]
  u16*   Vt   = (u16*)alloc(RD * 2);                          // [4][1024][2048]
  float* x2   = (float*)alloc(RD * 4);

  const size_t need_batched = o + (size_t)NB * SEQ * SEQ * 6 + 1024;
  const int NZ = (ws_size >= need_batched) ? NB : 1;
  float* Sbuf = (float*)alloc((size_t)NZ * SEQ * SEQ * 4);
  u16*   Pb   = (u16*)alloc((size_t)NZ * SEQ * SEQ * 2);
  u16*   ff   = (NZ == NB) ? (u16*)Sbuf
                           : (u16*)alloc((size_t)NB * SEQ * HID * 2);

  const dim3 blk(512);
  const dim3 tblk(32, 8);

  transpose_cast_f32<<<dim3(32, 32), tblk, 0, stream>>>(Wq, wqkT, EMBED, EMBED);
  transpose_cast_f32<<<dim3(32, 32), tblk, 0, stream>>>(Wk, wqkT + (size_t)EMBED * EMBED, EMBED, EMBED);
  transpose_cast_f32<<<dim3(32, 32), tblk, 0, stream>>>(Wv, wvT, EMBED, EMBED);
  transpose_cast_f32<<<dim3(HID / 32, EMBED / 32), tblk, 0, stream>>>(W1, w1T, EMBED, HID);
  transpose_cast_f32<<<dim3(EMBED / 32, HID / 32), tblk, 0, stream>>>(W2, w2T, HID, EMBED);
  concat_bias2<<<dim3(2), dim3(1024), 0, stream>>>(bq, bk, bqk);

  ln_kernel<<<dim3(NB * SEQ), dim3(256), 0, stream>>>(x, g1, be1, h);

  // QK projection: [8192][2048], 256x256 v2 tiles
  gemm256v2<0><<<dim3(2048 / 256, NB * SEQ / 256, 1), blk, 0, stream>>>(
      h, EMBED, 0LL, wqkT, EMBED, 0LL, QKb, 2048, 0LL, bqk, 1.f, EMBED);

  // V^T projection (direct): Vt[b][d][s] = sum_k WvT[d][k]*h[b,s,k] + bv[d]
  gemm8p<5><<<dim3(SEQ / 128, EMBED / 256, NB), blk, 0, stream>>>(
      wvT, EMBED, 0LL, h, EMBED, (long long)SEQ * EMBED,
      Vt, SEQ, (long long)EMBED * SEQ, bv, nullptr, 1.f, EMBED);

  // attention
  for (int b = 0; b < NB; b += NZ) {
    const u16* Qp  = QKb + (size_t)b * SEQ * 2048;
    const u16* Kp  = Qp + 1024;
    const u16* Vtp = Vt + (size_t)b * EMBED * SEQ;
    float* x2p     = x2 + (size_t)b * SEQ * EMBED;
    const float* xp = x + (size_t)b * SEQ * EMBED;
    gemm256v2<1><<<dim3(SEQ / 256, SEQ / 256, NZ), blk, 0, stream>>>(
        Qp, 2048, (long long)SEQ * 2048, Kp, 2048, (long long)SEQ * 2048,
        Sbuf, SEQ, (long long)SEQ * SEQ, nullptr, 0.03125f, EMBED);
    softmax_kernel<<<dim3(SEQ, NZ), dim3(256), 0, stream>>>(Sbuf, Pb);
    gemm8p<2><<<dim3(EMBED / 128, SEQ / 256, NZ), blk, 0, stream>>>(
        Pb, SEQ, (long long)SEQ * SEQ, Vtp, SEQ, (long long)EMBED * SEQ,
        x2p, EMBED, (long long)SEQ * EMBED, nullptr, xp, 1.f, SEQ);
  }

  ln_kernel<<<dim3(NB * SEQ), dim3(256), 0, stream>>>(x2, g2, be2, h);

  // MLP
  gemm256v2<3><<<dim3(HID / 256, NB * SEQ / 256, 1), blk, 0, stream>>>(
      h, EMBED, 0LL, w1T, EMBED, 0LL, ff, HID, 0LL, b1, 1.f, EMBED);
  gemm8p<4><<<dim3(EMBED / 128, NB * SEQ / 256, 1), blk, 0, stream>>>(
      ff, HID, 0LL, w2T, HID, 0LL, out, EMBED, 0LL, b2, x2, 1.f, HID);
}

// Round 7
// 333.003 us; speedup vs baseline: 1.0358x; 1.0358x over previous
//
#include <hip/hip_runtime.h>

#define EMBED 1024
#define HID   4096
#define NB    4
#define SEQ   2048

typedef __attribute__((ext_vector_type(8)))  __bf16 bf16x8;
typedef __attribute__((ext_vector_type(4)))  float  f32x4;
typedef __attribute__((ext_vector_type(4)))  int    i32x4;
typedef unsigned short u16;

__device__ __forceinline__ u16 f2bf(float f) {
  unsigned u = __float_as_uint(f);
  u += 0x7FFFu + ((u >> 16) & 1u);
  return (u16)(u >> 16);
}
__device__ __forceinline__ float bf2f(u16 u) {
  return __uint_as_float(((unsigned)u) << 16);
}

typedef const __attribute__((address_space(1))) unsigned int* gas_t;
typedef __attribute__((address_space(3))) unsigned int* las_t;
__device__ __forceinline__ void gld16(const void* g, void* l) {
  __builtin_amdgcn_global_load_lds((gas_t)g, (las_t)l, 16, 0, 0);
}

#define RD16(p)       __builtin_bit_cast(bf16x8, *(const i32x4*)(p))
#define MFMA16(a,b,c) __builtin_amdgcn_mfma_f32_16x16x32_bf16(a, b, c, 0, 0, 0)
#define SCHED0()      __builtin_amdgcn_sched_barrier(0)
#define BARR()        __builtin_amdgcn_s_barrier()
#define LGKM(n)       asm volatile("s_waitcnt lgkmcnt(" #n ")" ::: "memory")
#define VMW(n)        asm volatile("s_waitcnt vmcnt(" #n ")" ::: "memory")

// ---------------------------------------------------------------------------
// 256x256 NT GEMM (round-3 proven schedule, used for MLP1 only).
// BK=64, 512 thr (8 waves 2Mx4N, per-wave 128x64), 2 LDS buffers (128KB),
// 4 phases/K-tile x 16 MFMA, region-recycled staging, vmcnt(6) ledger.
// ---------------------------------------------------------------------------
template<int EPI>
__global__ __launch_bounds__(512, 2) void gemm256(
    const u16* __restrict__ A, int lda, long long astr,
    const u16* __restrict__ B, int ldb, long long bstr,
    void* __restrict__ C, int ldc, long long cstr,
    const float* __restrict__ bias,
    const float* __restrict__ add,
    float scale, int Kdim)
{
  __shared__ char lds[131072];   // buf b: A at b*65536, B at b*65536+32768

  const int tid  = threadIdx.x;
  const int lane = tid & 63;
  const int w    = tid >> 6;
  const int wr   = w >> 2, wc = w & 3;    // 2x4 waves -> 128x64 per wave
  const int l15  = lane & 15, l4 = lane >> 4;

  const int gx   = gridDim.x;
  const int nwg  = gx * gridDim.y;
  const int orig = blockIdx.y * gx + blockIdx.x;
  const int t    = ((nwg & 7) == 0) ? ((orig & 7) * (nwg >> 3) + (orig >> 3)) : orig;
  const int bx   = t % gx, by = t / gx;

  const u16* Ab = A + (size_t)blockIdx.z * astr + (size_t)by * 256 * lda;
  const u16* Bb = B + (size_t)blockIdx.z * bstr + (size_t)bx * 256 * ldb;

  const int    srow = tid >> 3;
  const size_t sa   = (size_t)srow * lda + (size_t)(((tid & 7) ^ (srow & 7)) * 8);
  const size_t sb   = (size_t)srow * ldb + (size_t)(((tid & 7) ^ (srow & 7)) * 8);
  const int    ldst = tid * 16;

  auto stA = [&](int buf, int q, int kk) {
    gld16(Ab + (size_t)(q * 64) * lda + kk + sa, lds + buf * 65536 + q * 8192 + ldst);
  };
  auto stB = [&](int buf, int i, int kk) {
    gld16(Bb + (size_t)(i * 64) * ldb + kk + sb, lds + buf * 65536 + 32768 + i * 8192 + ldst);
  };

  const int arow = (wr * 128 + l15) * 128;
  const int brow = 32768 + (wc * 64 + l15) * 128;
  const int cp0  = ((0 + l4) ^ (l15 & 7)) * 16;
  const int cp1  = ((4 + l4) ^ (l15 & 7)) * 16;

  f32x4 acc[8][4] = {};
  bf16x8 a0, a1, a2, a3, b0, b1, b2, b3, b4, b5, b6, b7;

  const int NT = Kdim >> 6;
  const int NI = NT >> 1;

#define BLOADS(LB) \
    b0 = RD16((LB) + brow + 0 * 2048 + cp0); \
    b1 = RD16((LB) + brow + 1 * 2048 + cp0); \
    b2 = RD16((LB) + brow + 2 * 2048 + cp0); \
    b3 = RD16((LB) + brow + 3 * 2048 + cp0); \
    b4 = RD16((LB) + brow + 0 * 2048 + cp1); \
    b5 = RD16((LB) + brow + 1 * 2048 + cp1); \
    b6 = RD16((LB) + brow + 2 * 2048 + cp1); \
    b7 = RD16((LB) + brow + 3 * 2048 + cp1);

#define PHASE(LB, MP, PRE, STG, VMST) do { \
    a0 = RD16((LB) + arow + (MP) * 4096 + cp0); \
    a1 = RD16((LB) + arow + (MP) * 4096 + cp1); \
    a2 = RD16((LB) + arow + (MP) * 4096 + 2048 + cp0); \
    a3 = RD16((LB) + arow + (MP) * 4096 + 2048 + cp1); \
    PRE STG VMST \
    SCHED0(); BARR(); LGKM(0); SCHED0(); \
    __builtin_amdgcn_s_setprio(1); \
    acc[2*(MP)  ][0] = MFMA16(a0, b0, acc[2*(MP)  ][0]); \
    acc[2*(MP)  ][1] = MFMA16(a0, b1, acc[2*(MP)  ][1]); \
    acc[2*(MP)  ][2] = MFMA16(a0, b2, acc[2*(MP)  ][2]); \
    acc[2*(MP)  ][3] = MFMA16(a0, b3, acc[2*(MP)  ][3]); \
    acc[2*(MP)+1][0] = MFMA16(a2, b0, acc[2*(MP)+1][0]); \
    acc[2*(MP)+1][1] = MFMA16(a2, b1, acc[2*(MP)+1][1]); \
    acc[2*(MP)+1][2] = MFMA16(a2, b2, acc[2*(MP)+1][2]); \
    acc[2*(MP)+1][3] = MFMA16(a2, b3, acc[2*(MP)+1][3]); \
    acc[2*(MP)  ][0] = MFMA16(a1, b4, acc[2*(MP)  ][0]); \
    acc[2*(MP)  ][1] = MFMA16(a1, b5, acc[2*(MP)  ][1]); \
    acc[2*(MP)  ][2] = MFMA16(a1, b6, acc[2*(MP)  ][2]); \
    acc[2*(MP)  ][3] = MFMA16(a1, b7, acc[2*(MP)  ][3]); \
    acc[2*(MP)+1][0] = MFMA16(a3, b4, acc[2*(MP)+1][0]); \
    acc[2*(MP)+1][1] = MFMA16(a3, b5, acc[2*(MP)+1][1]); \
    acc[2*(MP)+1][2] = MFMA16(a3, b6, acc[2*(MP)+1][2]); \
    acc[2*(MP)+1][3] = MFMA16(a3, b7, acc[2*(MP)+1][3]); \
    __builtin_amdgcn_s_setprio(0); \
    SCHED0(); BARR(); SCHED0(); \
  } while (0)

  stB(0, 0, 0); stB(0, 1, 0); stB(0, 2, 0); stB(0, 3, 0);
  stA(0, 0, 0); stA(0, 1, 0); stA(0, 2, 0); stA(0, 3, 0);
  stB(1, 0, 64); stB(1, 1, 64); stB(1, 2, 64); stB(1, 3, 64);
  stA(1, 0, 64); stA(1, 2, 64);
  VMW(6);
  BARR(); SCHED0();

  const char* L0 = lds;
  const char* L1 = lds + 65536;

  for (int I = 0; I < NI; ++I) {
    const bool st = (I + 1 < NI);
    const int k1 = (2 * I + 1) * 64;
    const int k2 = (2 * I + 2) * 64;
    const int k3 = (2 * I + 3) * 64;

    PHASE(L0, 0, BLOADS(L0), { stA(1, 1, k1); stA(1, 3, k1); }, ;);
    PHASE(L0, 1, ;, if (st) { stB(0, 0, k2); stB(0, 1, k2); }, ;);
    PHASE(L0, 2, ;, if (st) { stB(0, 2, k2); stB(0, 3, k2); }, ;);
    if (st) { PHASE(L0, 3, ;, { stA(0, 0, k2); stA(0, 2, k2); }, VMW(6);); }
    else    { PHASE(L0, 3, ;, ;, VMW(0);); }
    PHASE(L1, 0, BLOADS(L1), if (st) { stA(0, 1, k2); stA(0, 3, k2); }, ;);
    PHASE(L1, 1, ;, if (st) { stB(1, 0, k3); stB(1, 1, k3); }, ;);
    PHASE(L1, 2, ;, if (st) { stB(1, 2, k3); stB(1, 3, k3); }, ;);
    if (st) { PHASE(L1, 3, ;, { stA(1, 0, k3); stA(1, 2, k3); }, VMW(6);); }
    else    { PHASE(L1, 3, ;, ;, ;); }
  }
#undef PHASE
#undef BLOADS

  const int bm0 = by * 256 + wr * 128;
  const int bn0 = bx * 256 + wc * 64;
  float* Cf = (float*)C;
  u16*   Ch = (u16*)C;
  #pragma unroll
  for (int mi = 0; mi < 8; ++mi) {
    #pragma unroll
    for (int ni = 0; ni < 4; ++ni) {
      const int col = bn0 + ni * 16 + l15;
      const int r0  = bm0 + mi * 16 + l4 * 4;
      float bv = 0.f;
      if (EPI == 0 || EPI == 3 || EPI == 4) bv = bias[col];
      #pragma unroll
      for (int r = 0; r < 4; ++r) {
        const size_t idx = (size_t)blockIdx.z * cstr + (size_t)(r0 + r) * ldc + col;
        const float v = acc[mi][ni][r];
        if      (EPI == 0) Ch[idx] = f2bf(v + bv);
        else if (EPI == 1) Cf[idx] = v * scale;
        else if (EPI == 3) Ch[idx] = f2bf(fmaxf(v + bv, 0.f));
        else if (EPI == 4) Cf[idx] = v + bv + add[idx];
      }
    }
  }
}

// ---------------------------------------------------------------------------
// Deep-pipelined 256x128 NT GEMM (round-2/5 proven, barriers intact).
// EPI: 0 col-bias->bf16 | 1 *scale->f32 | 2 +add->f32 | 4 col-bias,+add->f32
//      5 row-bias->bf16 (direct V^T) | 6 *scale->bf16 (scores)
// ---------------------------------------------------------------------------
template<int EPI>
__global__ __launch_bounds__(512, 2) void gemm8p(
    const u16* __restrict__ A, int lda, long long astr,
    const u16* __restrict__ B, int ldb, long long bstr,
    void* __restrict__ C, int ldc, long long cstr,
    const float* __restrict__ bias,
    const float* __restrict__ add,
    float scale, int Kdim)
{
  __shared__ i32x4 lds4[9216];           // 3 slots x 48KB (A 32KB + B 16KB)
  const int SLOT = 49152;

  const int tid  = threadIdx.x;
  const int lane = tid & 63;
  const int w    = tid >> 6;
  const int wr   = w >> 1, wc = w & 1;
  const int l15  = lane & 15, l4 = lane >> 4;

  const int gx   = gridDim.x;
  const int nwg  = gx * gridDim.y;
  const int orig = blockIdx.y * gx + blockIdx.x;
  const int t    = ((nwg & 7) == 0) ? ((orig & 7) * (nwg >> 3) + (orig >> 3)) : orig;
  const int bx   = t % gx, by = t / gx;

  const u16* Ab = A + (size_t)blockIdx.z * astr + (size_t)by * 256 * lda;
  const u16* Bb = B + (size_t)blockIdx.z * bstr + (size_t)bx * 128 * ldb;

  size_t gaoff[4], gboff[2];
  #pragma unroll
  for (int i = 0; i < 4; ++i) {
    const int idx = i * 512 + tid, row = idx >> 3, gc = (idx & 7) ^ (row & 7);
    gaoff[i] = (size_t)row * lda + gc * 8;
  }
  #pragma unroll
  for (int j = 0; j < 2; ++j) {
    const int idx = j * 512 + tid, row = idx >> 3, gc = (idx & 7) ^ (row & 7);
    gboff[j] = (size_t)row * ldb + gc * 8;
  }

  int aoff[4], boff[4], cp16[2];
  #pragma unroll
  for (int m = 0; m < 4; ++m) aoff[m] = (wr * 64 + m * 16 + l15) * 128;
  #pragma unroll
  for (int n = 0; n < 4; ++n) boff[n] = 32768 + (wc * 64 + n * 16 + l15) * 128;
  cp16[0] = ((0 + l4) ^ (l15 & 7)) * 16;
  cp16[1] = ((4 + l4) ^ (l15 & 7)) * 16;

  f32x4 acc[4][4] = {};
  const int NT = Kdim >> 6;
  char* lbase = (char*)lds4;

  {
    char* s0 = lbase;
    char* s1 = lbase + SLOT;
    #pragma unroll
    for (int i = 0; i < 4; ++i) gld16(Ab + gaoff[i],      s0 + (i * 512 + w * 64) * 16);
    #pragma unroll
    for (int j = 0; j < 2; ++j) gld16(Bb + gboff[j],      s0 + 32768 + (j * 512 + w * 64) * 16);
    #pragma unroll
    for (int i = 0; i < 4; ++i) gld16(Ab + gaoff[i] + 64, s1 + (i * 512 + w * 64) * 16);
    #pragma unroll
    for (int j = 0; j < 2; ++j) gld16(Bb + gboff[j] + 64, s1 + 32768 + (j * 512 + w * 64) * 16);
  }

  int s = 0;
  for (int T = 0; T < NT; ++T) {
    const bool st  = (T + 2 < NT);
    const size_t kk = (size_t)(T + 2) * 64;
    const char* rA = lbase + s * SLOT;
    char* wS = lbase + ((s + 2 >= 3) ? (s - 1) : (s + 2)) * SLOT;

    if (T == NT - 1) VMW(0);
    else             VMW(6);
    BARR();
    SCHED0();

    bf16x8 b0, b1, b2, b3, a0, a1;

    b0 = RD16(rA + boff[0] + cp16[0]);
    b1 = RD16(rA + boff[1] + cp16[0]);
    b2 = RD16(rA + boff[2] + cp16[0]);
    b3 = RD16(rA + boff[3] + cp16[0]);
    a0 = RD16(rA + aoff[0] + cp16[0]);
    a1 = RD16(rA + aoff[1] + cp16[0]);
    if (st) {
      gld16(Ab + gaoff[0] + kk, wS + (0 * 512 + w * 64) * 16);
      gld16(Ab + gaoff[1] + kk, wS + (1 * 512 + w * 64) * 16);
    }
    BARR();
    LGKM(0);
    SCHED0();
    __builtin_amdgcn_s_setprio(1);
    acc[0][0] = MFMA16(a0, b0, acc[0][0]);
    acc[0][1] = MFMA16(a0, b1, acc[0][1]);
    acc[0][2] = MFMA16(a0, b2, acc[0][2]);
    acc[0][3] = MFMA16(a0, b3, acc[0][3]);
    acc[1][0] = MFMA16(a1, b0, acc[1][0]);
    acc[1][1] = MFMA16(a1, b1, acc[1][1]);
    acc[1][2] = MFMA16(a1, b2, acc[1][2]);
    acc[1][3] = MFMA16(a1, b3, acc[1][3]);
    __builtin_amdgcn_s_setprio(0);

    a0 = RD16(rA + aoff[2] + cp16[0]);
    a1 = RD16(rA + aoff[3] + cp16[0]);
    if (st) {
      gld16(Ab + gaoff[2] + kk, wS + (2 * 512 + w * 64) * 16);
      gld16(Ab + gaoff[3] + kk, wS + (3 * 512 + w * 64) * 16);
    }
    BARR();
    LGKM(0);
    SCHED0();
    __builtin_amdgcn_s_setprio(1);
    acc[2][0] = MFMA16(a0, b0, acc[2][0]);
    acc[2][1] = MFMA16(a0, b1, acc[2][1]);
    acc[2][2] = MFMA16(a0, b2, acc[2][2]);
    acc[2][3] = MFMA16(a0, b3, acc[2][3]);
    acc[3][0] = MFMA16(a1, b0, acc[3][0]);
    acc[3][1] = MFMA16(a1, b1, acc[3][1]);
    acc[3][2] = MFMA16(a1, b2, acc[3][2]);
    acc[3][3] = MFMA16(a1, b3, acc[3][3]);
    __builtin_amdgcn_s_setprio(0);

    b0 = RD16(rA + boff[0] + cp16[1]);
    b1 = RD16(rA + boff[1] + cp16[1]);
    b2 = RD16(rA + boff[2] + cp16[1]);
    b3 = RD16(rA + boff[3] + cp16[1]);
    a0 = RD16(rA + aoff[0] + cp16[1]);
    a1 = RD16(rA + aoff[1] + cp16[1]);
    if (st) {
      gld16(Bb + gboff[0] + kk, wS + 32768 + (0 * 512 + w * 64) * 16);
    }
    BARR();
    LGKM(0);
    SCHED0();
    __builtin_amdgcn_s_setprio(1);
    acc[0][0] = MFMA16(a0, b0, acc[0][0]);
    acc[0][1] = MFMA16(a0, b1, acc[0][1]);
    acc[0][2] = MFMA16(a0, b2, acc[0][2]);
    acc[0][3] = MFMA16(a0, b3, acc[0][3]);
    acc[1][0] = MFMA16(a1, b0, acc[1][0]);
    acc[1][1] = MFMA16(a1, b1, acc[1][1]);
    acc[1][2] = MFMA16(a1, b2, acc[1][2]);
    acc[1][3] = MFMA16(a1, b3, acc[1][3]);
    __builtin_amdgcn_s_setprio(0);

    a0 = RD16(rA + aoff[2] + cp16[1]);
    a1 = RD16(rA + aoff[3] + cp16[1]);
    if (st) {
      gld16(Bb + gboff[1] + kk, wS + 32768 + (1 * 512 + w * 64) * 16);
    }
    BARR();
    LGKM(0);
    SCHED0();
    __builtin_amdgcn_s_setprio(1);
    acc[2][0] = MFMA16(a0, b0, acc[2][0]);
    acc[2][1] = MFMA16(a0, b1, acc[2][1]);
    acc[2][2] = MFMA16(a0, b2, acc[2][2]);
    acc[2][3] = MFMA16(a0, b3, acc[2][3]);
    acc[3][0] = MFMA16(a1, b0, acc[3][0]);
    acc[3][1] = MFMA16(a1, b1, acc[3][1]);
    acc[3][2] = MFMA16(a1, b2, acc[3][2]);
    acc[3][3] = MFMA16(a1, b3, acc[3][3]);
    __builtin_amdgcn_s_setprio(0);

    s = (s + 1 == 3) ? 0 : s + 1;
  }

  const int bm0 = by * 256 + wr * 64;
  const int bn0 = bx * 128 + wc * 64;
  float* Cf = (float*)C;
  u16*   Ch = (u16*)C;
  #pragma unroll
  for (int mi = 0; mi < 4; ++mi) {
    #pragma unroll
    for (int ni = 0; ni < 4; ++ni) {
      const int col = bn0 + ni * 16 + l15;
      const int r0  = bm0 + mi * 16 + l4 * 4;
      float bv = 0.f;
      if (EPI == 0 || EPI == 4) bv = bias[col];
      #pragma unroll
      for (int r = 0; r < 4; ++r) {
        const size_t idx = (size_t)blockIdx.z * cstr + (size_t)(r0 + r) * ldc + col;
        const float v = acc[mi][ni][r];
        if      (EPI == 0) Ch[idx] = f2bf(v + bv);
        else if (EPI == 1) Cf[idx] = v * scale;
        else if (EPI == 2) Cf[idx] = v + add[idx];
        else if (EPI == 4) Cf[idx] = v + bv + add[idx];
        else if (EPI == 5) Ch[idx] = f2bf(v + bias[r0 + r]);
        else if (EPI == 6) Ch[idx] = f2bf(v * scale);
      }
    }
  }
}

// ---------------------------------------------------------------------------
__global__ __launch_bounds__(256) void ln_kernel(
    const float* __restrict__ x, const float* __restrict__ g,
    const float* __restrict__ be, u16* __restrict__ out)
{
  const int row = blockIdx.x;
  const int tid = threadIdx.x;
  const float4 v = ((const float4*)(x + (size_t)row * EMBED))[tid];
  float s  = v.x + v.y + v.z + v.w;
  float s2 = v.x * v.x + v.y * v.y + v.z * v.z + v.w * v.w;
  #pragma unroll
  for (int m = 1; m < 64; m <<= 1) { s += __shfl_xor(s, m); s2 += __shfl_xor(s2, m); }
  __shared__ float ls[4], ls2[4];
  const int w = tid >> 6;
  if ((tid & 63) == 0) { ls[w] = s; ls2[w] = s2; }
  __syncthreads();
  s  = ls[0] + ls[1] + ls[2] + ls[3];
  s2 = ls2[0] + ls2[1] + ls2[2] + ls2[3];
  const float mu   = s * (1.f / EMBED);
  const float var  = s2 * (1.f / EMBED) - mu * mu;
  const float rstd = rsqrtf(var + 1e-5f);
  const float4 gv = ((const float4*)g)[tid];
  const float4 bv = ((const float4*)be)[tid];
  ushort4 o;
  o.x = f2bf((v.x - mu) * rstd * gv.x + bv.x);
  o.y = f2bf((v.y - mu) * rstd * gv.y + bv.y);
  o.z = f2bf((v.z - mu) * rstd * gv.z + bv.z);
  o.w = f2bf((v.w - mu) * rstd * gv.w + bv.w);
  ((ushort4*)(out + (size_t)row * EMBED))[tid] = o;
}

// ---------------------------------------------------------------------------
// Row softmax over bf16 scores: S bf16 [2048] -> P bf16
// ---------------------------------------------------------------------------
__global__ __launch_bounds__(256) void softmax_bf16(
    const u16* __restrict__ S, u16* __restrict__ P)
{
  const int tid = threadIdx.x;
  const size_t base = ((size_t)blockIdx.y * SEQ + blockIdx.x) * SEQ;
  const ushort4* src = (const ushort4*)(S + base);
  const ushort4 ua = src[tid];
  const ushort4 ub = src[tid + 256];
  float a0 = bf2f(ua.x), a1 = bf2f(ua.y), a2 = bf2f(ua.z), a3 = bf2f(ua.w);
  float b0 = bf2f(ub.x), b1 = bf2f(ub.y), b2 = bf2f(ub.z), b3 = bf2f(ub.w);
  float m = fmaxf(fmaxf(fmaxf(a0, a1), fmaxf(a2, a3)),
                  fmaxf(fmaxf(b0, b1), fmaxf(b2, b3)));
  #pragma unroll
  for (int msk = 1; msk < 64; msk <<= 1) m = fmaxf(m, __shfl_xor(m, msk));
  __shared__ float red[8];
  const int w = tid >> 6;
  if ((tid & 63) == 0) red[w] = m;
  __syncthreads();
  m = fmaxf(fmaxf(red[0], red[1]), fmaxf(red[2], red[3]));
  a0 = __expf(a0 - m); a1 = __expf(a1 - m); a2 = __expf(a2 - m); a3 = __expf(a3 - m);
  b0 = __expf(b0 - m); b1 = __expf(b1 - m); b2 = __expf(b2 - m); b3 = __expf(b3 - m);
  float s = a0 + a1 + a2 + a3 + b0 + b1 + b2 + b3;
  #pragma unroll
  for (int msk = 1; msk < 64; msk <<= 1) s += __shfl_xor(s, msk);
  if ((tid & 63) == 0) red[4 + w] = s;
  __syncthreads();
  s = red[4] + red[5] + red[6] + red[7];
  const float inv = 1.0f / s;
  ushort4 oa, ob;
  oa.x = f2bf(a0 * inv); oa.y = f2bf(a1 * inv); oa.z = f2bf(a2 * inv); oa.w = f2bf(a3 * inv);
  ob.x = f2bf(b0 * inv); ob.y = f2bf(b1 * inv); ob.z = f2bf(b2 * inv); ob.w = f2bf(b3 * inv);
  ushort4* dst = (ushort4*)(P + base);
  dst[tid]       = oa;
  dst[tid + 256] = ob;
}

// ---------------------------------------------------------------------------
// Transpose + cast: W f32 [K][N] -> Wt bf16 [N][K] (z-batched square version)
// ---------------------------------------------------------------------------
__global__ void transpose_cast3(const float* __restrict__ W0,
                                const float* __restrict__ W1_,
                                const float* __restrict__ W2_,
                                u16* __restrict__ Wt)
{
  __shared__ float t[32][33];
  const int z = blockIdx.z;
  const float* W = (z == 0) ? W0 : (z == 1) ? W1_ : W2_;
  u16* dst = Wt + (size_t)z * EMBED * EMBED;
  const int tx = threadIdx.x, ty = threadIdx.y;
  const int n0 = blockIdx.x * 32, k0 = blockIdx.y * 32;
  #pragma unroll
  for (int i = 0; i < 4; ++i)
    t[ty + i * 8][tx] = W[(size_t)(k0 + ty + i * 8) * EMBED + n0 + tx];
  __syncthreads();
  #pragma unroll
  for (int i = 0; i < 4; ++i)
    dst[(size_t)(n0 + ty + i * 8) * EMBED + k0 + tx] = f2bf(t[tx][ty + i * 8]);
}

__global__ void transpose_cast_f32(const float* __restrict__ W, u16* __restrict__ Wt,
                                   int K, int N)
{
  __shared__ float t[32][33];
  const int tx = threadIdx.x, ty = threadIdx.y;
  const int n0 = blockIdx.x * 32, k0 = blockIdx.y * 32;
  #pragma unroll
  for (int i = 0; i < 4; ++i)
    t[ty + i * 8][tx] = W[(size_t)(k0 + ty + i * 8) * N + n0 + tx];
  __syncthreads();
  #pragma unroll
  for (int i = 0; i < 4; ++i)
    Wt[(size_t)(n0 + ty + i * 8) * K + k0 + tx] = f2bf(t[tx][ty + i * 8]);
}

__global__ void concat_bias2(const float* __restrict__ a, const float* __restrict__ b,
                             float* __restrict__ o)
{
  const int i = blockIdx.x * 1024 + threadIdx.x;
  o[i] = (i < 1024) ? a[i] : b[i - 1024];
}

// ---------------------------------------------------------------------------
extern "C" void kernel_launch(void* const* d_in, const int* in_sizes, int n_in,
                              void* d_out, int out_size, void* d_ws, size_t ws_size,
                              hipStream_t stream)
{
  const float* x   = (const float*)d_in[0];
  const float* Wq  = (const float*)d_in[1];
  const float* bq  = (const float*)d_in[2];
  const float* Wk  = (const float*)d_in[3];
  const float* bk  = (const float*)d_in[4];
  const float* Wv  = (const float*)d_in[5];
  const float* bv  = (const float*)d_in[6];
  const float* W1  = (const float*)d_in[7];
  const float* b1  = (const float*)d_in[8];
  const float* W2  = (const float*)d_in[9];
  const float* b2  = (const float*)d_in[10];
  const float* g1  = (const float*)d_in[11];
  const float* be1 = (const float*)d_in[12];
  const float* g2  = (const float*)d_in[13];
  const float* be2 = (const float*)d_in[14];
  float* out = (float*)d_out;

  const size_t RD = (size_t)NB * SEQ * EMBED;

  char* base = (char*)d_ws;
  size_t o = 0;
  auto alloc = [&](size_t bytes) -> void* {
    o = (o + 255) & ~(size_t)255;
    void* p = base + o;
    o += bytes;
    return p;
  };

  // wqkv3T: [Q;K;V] transposed weights contiguous [3072][1024]
  u16*   wqkv3T = (u16*)alloc((size_t)3 * EMBED * EMBED * 2);
  u16*   w1T    = (u16*)alloc((size_t)HID * EMBED * 2);
  u16*   w2T    = (u16*)alloc((size_t)EMBED * HID * 2);
  float* bqk    = (float*)alloc(2048 * 4);
  u16*   h      = (u16*)alloc(RD * 2);
  u16*   QKb    = (u16*)alloc(RD * 2 * 2);                    // [8192][2048]
  u16*   Vt     = (u16*)alloc(RD * 2);                        // [4][1024][2048]
  float* x2     = (float*)alloc(RD * 4);

  // attention scratch: S and P both bf16 now (32MB+32MB at NZ=4)
  const size_t need_batched = o + (size_t)NB * SEQ * SEQ * 4 + 1024;
  const int NZ = (ws_size >= need_batched) ? NB : 1;
  u16* Sb16 = (u16*)alloc((size_t)NZ * SEQ * SEQ * 2);
  u16* Pb   = (u16*)alloc((size_t)NZ * SEQ * SEQ * 2);
  u16* ff   = (NZ == NB) ? Sb16                                // 64MB alias (S+P dead)
                         : (u16*)alloc((size_t)NB * SEQ * HID * 2);

  const u16* wqkT = wqkv3T;                                    // [2048][1024]
  const u16* wvT  = wqkv3T + (size_t)2 * EMBED * EMBED;        // [1024][1024]

  const dim3 blk(512);
  const dim3 tblk(32, 8);

  // weights -> bf16 [N][K]: one z=3 launch for the square ones
  transpose_cast3<<<dim3(32, 32, 3), tblk, 0, stream>>>(Wq, Wk, Wv, wqkv3T);
  transpose_cast_f32<<<dim3(HID / 32, EMBED / 32), tblk, 0, stream>>>(W1, w1T, EMBED, HID);
  transpose_cast_f32<<<dim3(EMBED / 32, HID / 32), tblk, 0, stream>>>(W2, w2T, HID, EMBED);
  concat_bias2<<<dim3(2), dim3(1024), 0, stream>>>(bq, bk, bqk);

  // LN1
  ln_kernel<<<dim3(NB * SEQ), dim3(256), 0, stream>>>(x, g1, be1, h);

  // QK projection: [8192][2048]
  gemm8p<0><<<dim3(2048 / 128, NB * SEQ / 256, 1), blk, 0, stream>>>(
      h, EMBED, 0LL, wqkT, EMBED, 0LL, QKb, 2048, 0LL, bqk, nullptr, 1.f, EMBED);

  // V^T projection (direct): Vt[b][d][s] = sum_k wvT[d][k]*h[b,s,k] + bv[d]
  gemm8p<5><<<dim3(SEQ / 128, EMBED / 256, NB), blk, 0, stream>>>(
      wvT, EMBED, 0LL, h, EMBED, (long long)SEQ * EMBED,
      Vt, SEQ, (long long)EMBED * SEQ, bv, nullptr, 1.f, EMBED);

  // attention: scores (bf16 S) -> softmax -> PV (+ residual into x2)
  for (int b = 0; b < NB; b += NZ) {
    const u16* Qp  = QKb + (size_t)b * SEQ * 2048;
    const u16* Kp  = Qp + 1024;
    const u16* Vtp = Vt + (size_t)b * EMBED * SEQ;
    float* x2p     = x2 + (size_t)b * SEQ * EMBED;
    const float* xp = x + (size_t)b * SEQ * EMBED;
    gemm8p<6><<<dim3(SEQ / 128, SEQ / 256, NZ), blk, 0, stream>>>(
        Qp, 2048, (long long)SEQ * 2048, Kp, 2048, (long long)SEQ * 2048,
        Sb16, SEQ, (long long)SEQ * SEQ, nullptr, nullptr, 0.03125f, EMBED);
    softmax_bf16<<<dim3(SEQ, NZ), dim3(256), 0, stream>>>(Sb16, Pb);
    gemm8p<2><<<dim3(EMBED / 128, SEQ / 256, NZ), blk, 0, stream>>>(
        Pb, SEQ, (long long)SEQ * SEQ, Vtp, SEQ, (long long)EMBED * SEQ,
        x2p, EMBED, (long long)SEQ * EMBED, nullptr, xp, 1.f, SEQ);
  }

  // LN2
  ln_kernel<<<dim3(NB * SEQ), dim3(256), 0, stream>>>(x2, g2, be2, h);

  // MLP
  gemm256<3><<<dim3(HID / 256, NB * SEQ / 256, 1), blk, 0, stream>>>(
      h, EMBED, 0LL, w1T, EMBED, 0LL, ff, HID, 0LL, b1, nullptr, 1.f, EMBED);
  gemm8p<4><<<dim3(EMBED / 128, NB * SEQ / 256, 1), blk, 0, stream>>>(
      ff, HID, 0LL, w2T, HID, 0LL, out, EMBED, 0LL, b2, x2, 1.f, HID);
}

// Round 8
// 321.949 us; speedup vs baseline: 1.0713x; 1.0343x over previous
//
#include <hip/hip_runtime.h>

#define EMBED 1024
#define HID   4096
#define NB    4
#define SEQ   2048

typedef __attribute__((ext_vector_type(8)))  __bf16 bf16x8;
typedef __attribute__((ext_vector_type(4)))  float  f32x4;
typedef __attribute__((ext_vector_type(4)))  int    i32x4;
typedef unsigned short u16;

__device__ __forceinline__ u16 f2bf(float f) {
  unsigned u = __float_as_uint(f);
  u += 0x7FFFu + ((u >> 16) & 1u);
  return (u16)(u >> 16);
}
__device__ __forceinline__ float bf2f(u16 u) {
  return __uint_as_float(((unsigned)u) << 16);
}

typedef const __attribute__((address_space(1))) unsigned int* gas_t;
typedef __attribute__((address_space(3))) unsigned int* las_t;
__device__ __forceinline__ void gld16(const void* g, void* l) {
  __builtin_amdgcn_global_load_lds((gas_t)g, (las_t)l, 16, 0, 0);
}

#define RD16(p)       __builtin_bit_cast(bf16x8, *(const i32x4*)(p))
#define MFMA16(a,b,c) __builtin_amdgcn_mfma_f32_16x16x32_bf16(a, b, c, 0, 0, 0)
#define SCHED0()      __builtin_amdgcn_sched_barrier(0)
#define BARR()        __builtin_amdgcn_s_barrier()
#define LGKM(n)       asm volatile("s_waitcnt lgkmcnt(" #n ")" ::: "memory")
#define VMW(n)        asm volatile("s_waitcnt vmcnt(" #n ")" ::: "memory")

// ---------------------------------------------------------------------------
// 256x256 NT GEMM v3: one barrier per K-tile, NO explicit lgkmcnt — the
// compiler emits counted lgkm waits and interleaves ds_read drain under
// MFMAs (the explicit LGKM(0) drains in v1/v2 were the serializer).
// BK=64, 512 thr (8 waves 2Mx4N, per-wave 128x64), 2 LDS buffers (128KB),
// stage lead = 1 tile: all 8 stage units issued at tile top into buf^1
// (fully consumed in tile T-1; its readers retired before this barrier).
// EPI: 0 bias->bf16 | 3 bias,relu->bf16 | 6 *scale->bf16
// ---------------------------------------------------------------------------
template<int EPI>
__global__ __launch_bounds__(512, 2) void gemm256v3(
    const u16* __restrict__ A, int lda, long long astr,
    const u16* __restrict__ B, int ldb, long long bstr,
    void* __restrict__ C, int ldc, long long cstr,
    const float* __restrict__ bias,
    float scale, int Kdim)
{
  __shared__ char lds[131072];   // buf b: A at b*65536, B at b*65536+32768

  const int tid  = threadIdx.x;
  const int lane = tid & 63;
  const int w    = tid >> 6;
  const int wr   = w >> 2, wc = w & 3;    // 2x4 waves -> 128x64 per wave
  const int l15  = lane & 15, l4 = lane >> 4;

  const int gx   = gridDim.x;
  const int nwg  = gx * gridDim.y;
  const int orig = blockIdx.y * gx + blockIdx.x;
  const int t    = ((nwg & 7) == 0) ? ((orig & 7) * (nwg >> 3) + (orig >> 3)) : orig;
  const int bx   = t % gx, by = t / gx;

  const u16* Ab = A + (size_t)blockIdx.z * astr + (size_t)by * 256 * lda;
  const u16* Bb = B + (size_t)blockIdx.z * bstr + (size_t)bx * 256 * ldb;

  // staging: 8KB per issue (512 thr x 16B), linear LDS dest, pre-swizzled src
  const int    srow = tid >> 3;
  const size_t sa   = (size_t)srow * lda + (size_t)(((tid & 7) ^ (srow & 7)) * 8);
  const size_t sb   = (size_t)srow * ldb + (size_t)(((tid & 7) ^ (srow & 7)) * 8);
  const int    ldst = tid * 16;

  auto stA = [&](int buf, int q, int kk) {
    gld16(Ab + (size_t)(q * 64) * lda + kk + sa, lds + buf * 65536 + q * 8192 + ldst);
  };
  auto stB = [&](int buf, int i, int kk) {
    gld16(Bb + (size_t)(i * 64) * ldb + kk + sb, lds + buf * 65536 + 32768 + i * 8192 + ldst);
  };

  // LDS read offsets: row*128B, chunk XOR (row&7) swizzle (0-conflict, proven)
  const int arow = (wr * 128 + l15) * 128;
  const int brow = 32768 + (wc * 64 + l15) * 128;
  const int cp0  = ((0 + l4) ^ (l15 & 7)) * 16;
  const int cp1  = ((4 + l4) ^ (l15 & 7)) * 16;

  f32x4 acc[8][4] = {};
  const int NT = Kdim >> 6;

  // prologue: stage tile0 into buf0
  stB(0, 0, 0); stB(0, 1, 0); stB(0, 2, 0); stB(0, 3, 0);
  stA(0, 0, 0); stA(0, 1, 0); stA(0, 2, 0); stA(0, 3, 0);

  for (int T = 0; T < NT; ++T) {
    const char* LB = lds + (T & 1) * 65536;
    VMW(0);          // buf (T&1) stages (issued last tile / prologue) landed
    SCHED0();
    BARR();          // all waves' stages visible; all T-1 readers retired
    SCHED0();

    if (T + 1 < NT) {
      const int b = (T & 1) ^ 1, kk = (T + 1) * 64;
      stB(b, 0, kk); stB(b, 1, kk); stB(b, 2, kk); stB(b, 3, kk);
      stA(b, 0, kk); stA(b, 1, kk); stA(b, 2, kk); stA(b, 3, kk);
    }

    // ---- all 24 ds_reads + 64 MFMAs, compiler-scheduled (counted waits) ---
    bf16x8 b0 = RD16(LB + brow + 0 * 2048 + cp0);
    bf16x8 b1 = RD16(LB + brow + 1 * 2048 + cp0);
    bf16x8 b2 = RD16(LB + brow + 2 * 2048 + cp0);
    bf16x8 b3 = RD16(LB + brow + 3 * 2048 + cp0);
    bf16x8 b4 = RD16(LB + brow + 0 * 2048 + cp1);
    bf16x8 b5 = RD16(LB + brow + 1 * 2048 + cp1);
    bf16x8 b6 = RD16(LB + brow + 2 * 2048 + cp1);
    bf16x8 b7 = RD16(LB + brow + 3 * 2048 + cp1);

#define AQ(MP, x0, x1, x2, x3) \
    bf16x8 x0 = RD16(LB + arow + (MP) * 4096 + cp0); \
    bf16x8 x1 = RD16(LB + arow + (MP) * 4096 + cp1); \
    bf16x8 x2 = RD16(LB + arow + (MP) * 4096 + 2048 + cp0); \
    bf16x8 x3 = RD16(LB + arow + (MP) * 4096 + 2048 + cp1);

#define MQ(MP, x0, x1, x2, x3) \
    acc[2*(MP)  ][0] = MFMA16(x0, b0, acc[2*(MP)  ][0]); \
    acc[2*(MP)  ][1] = MFMA16(x0, b1, acc[2*(MP)  ][1]); \
    acc[2*(MP)  ][2] = MFMA16(x0, b2, acc[2*(MP)  ][2]); \
    acc[2*(MP)  ][3] = MFMA16(x0, b3, acc[2*(MP)  ][3]); \
    acc[2*(MP)+1][0] = MFMA16(x2, b0, acc[2*(MP)+1][0]); \
    acc[2*(MP)+1][1] = MFMA16(x2, b1, acc[2*(MP)+1][1]); \
    acc[2*(MP)+1][2] = MFMA16(x2, b2, acc[2*(MP)+1][2]); \
    acc[2*(MP)+1][3] = MFMA16(x2, b3, acc[2*(MP)+1][3]); \
    acc[2*(MP)  ][0] = MFMA16(x1, b4, acc[2*(MP)  ][0]); \
    acc[2*(MP)  ][1] = MFMA16(x1, b5, acc[2*(MP)  ][1]); \
    acc[2*(MP)  ][2] = MFMA16(x1, b6, acc[2*(MP)  ][2]); \
    acc[2*(MP)  ][3] = MFMA16(x1, b7, acc[2*(MP)  ][3]); \
    acc[2*(MP)+1][0] = MFMA16(x3, b4, acc[2*(MP)+1][0]); \
    acc[2*(MP)+1][1] = MFMA16(x3, b5, acc[2*(MP)+1][1]); \
    acc[2*(MP)+1][2] = MFMA16(x3, b6, acc[2*(MP)+1][2]); \
    acc[2*(MP)+1][3] = MFMA16(x3, b7, acc[2*(MP)+1][3]);

    AQ(0, a00, a01, a02, a03)
    AQ(1, a10, a11, a12, a13)
    MQ(0, a00, a01, a02, a03)
    AQ(2, a20, a21, a22, a23)
    MQ(1, a10, a11, a12, a13)
    AQ(3, a30, a31, a32, a33)
    MQ(2, a20, a21, a22, a23)
    MQ(3, a30, a31, a32, a33)
#undef AQ
#undef MQ
  }

  // epilogue: C/D layout col=lane&15, row=(lane>>4)*4+reg (m89)
  const int bm0 = by * 256 + wr * 128;
  const int bn0 = bx * 256 + wc * 64;
  u16* Ch = (u16*)C;
  #pragma unroll
  for (int mi = 0; mi < 8; ++mi) {
    #pragma unroll
    for (int ni = 0; ni < 4; ++ni) {
      const int col = bn0 + ni * 16 + l15;
      const int r0  = bm0 + mi * 16 + l4 * 4;
      float bv = 0.f;
      if (EPI == 0 || EPI == 3) bv = bias[col];
      #pragma unroll
      for (int r = 0; r < 4; ++r) {
        const size_t idx = (size_t)blockIdx.z * cstr + (size_t)(r0 + r) * ldc + col;
        const float v = acc[mi][ni][r];
        if      (EPI == 0) Ch[idx] = f2bf(v + bv);
        else if (EPI == 3) Ch[idx] = f2bf(fmaxf(v + bv, 0.f));
        else if (EPI == 6) Ch[idx] = f2bf(v * scale);
      }
    }
  }
}

// ---------------------------------------------------------------------------
// Deep-pipelined 256x128 NT GEMM (round-2/5 proven, untouched).
// EPI: 0 col-bias->bf16 | 1 *scale->f32 | 2 +add->f32 | 4 col-bias,+add->f32
//      5 row-bias->bf16 (direct V^T) | 6 *scale->bf16 (scores)
// ---------------------------------------------------------------------------
template<int EPI>
__global__ __launch_bounds__(512, 2) void gemm8p(
    const u16* __restrict__ A, int lda, long long astr,
    const u16* __restrict__ B, int ldb, long long bstr,
    void* __restrict__ C, int ldc, long long cstr,
    const float* __restrict__ bias,
    const float* __restrict__ add,
    float scale, int Kdim)
{
  __shared__ i32x4 lds4[9216];           // 3 slots x 48KB (A 32KB + B 16KB)
  const int SLOT = 49152;

  const int tid  = threadIdx.x;
  const int lane = tid & 63;
  const int w    = tid >> 6;
  const int wr   = w >> 1, wc = w & 1;
  const int l15  = lane & 15, l4 = lane >> 4;

  const int gx   = gridDim.x;
  const int nwg  = gx * gridDim.y;
  const int orig = blockIdx.y * gx + blockIdx.x;
  const int t    = ((nwg & 7) == 0) ? ((orig & 7) * (nwg >> 3) + (orig >> 3)) : orig;
  const int bx   = t % gx, by = t / gx;

  const u16* Ab = A + (size_t)blockIdx.z * astr + (size_t)by * 256 * lda;
  const u16* Bb = B + (size_t)blockIdx.z * bstr + (size_t)bx * 128 * ldb;

  size_t gaoff[4], gboff[2];
  #pragma unroll
  for (int i = 0; i < 4; ++i) {
    const int idx = i * 512 + tid, row = idx >> 3, gc = (idx & 7) ^ (row & 7);
    gaoff[i] = (size_t)row * lda + gc * 8;
  }
  #pragma unroll
  for (int j = 0; j < 2; ++j) {
    const int idx = j * 512 + tid, row = idx >> 3, gc = (idx & 7) ^ (row & 7);
    gboff[j] = (size_t)row * ldb + gc * 8;
  }

  int aoff[4], boff[4], cp16[2];
  #pragma unroll
  for (int m = 0; m < 4; ++m) aoff[m] = (wr * 64 + m * 16 + l15) * 128;
  #pragma unroll
  for (int n = 0; n < 4; ++n) boff[n] = 32768 + (wc * 64 + n * 16 + l15) * 128;
  cp16[0] = ((0 + l4) ^ (l15 & 7)) * 16;
  cp16[1] = ((4 + l4) ^ (l15 & 7)) * 16;

  f32x4 acc[4][4] = {};
  const int NT = Kdim >> 6;
  char* lbase = (char*)lds4;

  {
    char* s0 = lbase;
    char* s1 = lbase + SLOT;
    #pragma unroll
    for (int i = 0; i < 4; ++i) gld16(Ab + gaoff[i],      s0 + (i * 512 + w * 64) * 16);
    #pragma unroll
    for (int j = 0; j < 2; ++j) gld16(Bb + gboff[j],      s0 + 32768 + (j * 512 + w * 64) * 16);
    #pragma unroll
    for (int i = 0; i < 4; ++i) gld16(Ab + gaoff[i] + 64, s1 + (i * 512 + w * 64) * 16);
    #pragma unroll
    for (int j = 0; j < 2; ++j) gld16(Bb + gboff[j] + 64, s1 + 32768 + (j * 512 + w * 64) * 16);
  }

  int s = 0;
  for (int T = 0; T < NT; ++T) {
    const bool st  = (T + 2 < NT);
    const size_t kk = (size_t)(T + 2) * 64;
    const char* rA = lbase + s * SLOT;
    char* wS = lbase + ((s + 2 >= 3) ? (s - 1) : (s + 2)) * SLOT;

    if (T == NT - 1) VMW(0);
    else             VMW(6);
    BARR();
    SCHED0();

    bf16x8 b0, b1, b2, b3, a0, a1;

    b0 = RD16(rA + boff[0] + cp16[0]);
    b1 = RD16(rA + boff[1] + cp16[0]);
    b2 = RD16(rA + boff[2] + cp16[0]);
    b3 = RD16(rA + boff[3] + cp16[0]);
    a0 = RD16(rA + aoff[0] + cp16[0]);
    a1 = RD16(rA + aoff[1] + cp16[0]);
    if (st) {
      gld16(Ab + gaoff[0] + kk, wS + (0 * 512 + w * 64) * 16);
      gld16(Ab + gaoff[1] + kk, wS + (1 * 512 + w * 64) * 16);
    }
    BARR();
    LGKM(0);
    SCHED0();
    __builtin_amdgcn_s_setprio(1);
    acc[0][0] = MFMA16(a0, b0, acc[0][0]);
    acc[0][1] = MFMA16(a0, b1, acc[0][1]);
    acc[0][2] = MFMA16(a0, b2, acc[0][2]);
    acc[0][3] = MFMA16(a0, b3, acc[0][3]);
    acc[1][0] = MFMA16(a1, b0, acc[1][0]);
    acc[1][1] = MFMA16(a1, b1, acc[1][1]);
    acc[1][2] = MFMA16(a1, b2, acc[1][2]);
    acc[1][3] = MFMA16(a1, b3, acc[1][3]);
    __builtin_amdgcn_s_setprio(0);

    a0 = RD16(rA + aoff[2] + cp16[0]);
    a1 = RD16(rA + aoff[3] + cp16[0]);
    if (st) {
      gld16(Ab + gaoff[2] + kk, wS + (2 * 512 + w * 64) * 16);
      gld16(Ab + gaoff[3] + kk, wS + (3 * 512 + w * 64) * 16);
    }
    BARR();
    LGKM(0);
    SCHED0();
    __builtin_amdgcn_s_setprio(1);
    acc[2][0] = MFMA16(a0, b0, acc[2][0]);
    acc[2][1] = MFMA16(a0, b1, acc[2][1]);
    acc[2][2] = MFMA16(a0, b2, acc[2][2]);
    acc[2][3] = MFMA16(a0, b3, acc[2][3]);
    acc[3][0] = MFMA16(a1, b0, acc[3][0]);
    acc[3][1] = MFMA16(a1, b1, acc[3][1]);
    acc[3][2] = MFMA16(a1, b2, acc[3][2]);
    acc[3][3] = MFMA16(a1, b3, acc[3][3]);
    __builtin_amdgcn_s_setprio(0);

    b0 = RD16(rA + boff[0] + cp16[1]);
    b1 = RD16(rA + boff[1] + cp16[1]);
    b2 = RD16(rA + boff[2] + cp16[1]);
    b3 = RD16(rA + boff[3] + cp16[1]);
    a0 = RD16(rA + aoff[0] + cp16[1]);
    a1 = RD16(rA + aoff[1] + cp16[1]);
    if (st) {
      gld16(Bb + gboff[0] + kk, wS + 32768 + (0 * 512 + w * 64) * 16);
    }
    BARR();
    LGKM(0);
    SCHED0();
    __builtin_amdgcn_s_setprio(1);
    acc[0][0] = MFMA16(a0, b0, acc[0][0]);
    acc[0][1] = MFMA16(a0, b1, acc[0][1]);
    acc[0][2] = MFMA16(a0, b2, acc[0][2]);
    acc[0][3] = MFMA16(a0, b3, acc[0][3]);
    acc[1][0] = MFMA16(a1, b0, acc[1][0]);
    acc[1][1] = MFMA16(a1, b1, acc[1][1]);
    acc[1][2] = MFMA16(a1, b2, acc[1][2]);
    acc[1][3] = MFMA16(a1, b3, acc[1][3]);
    __builtin_amdgcn_s_setprio(0);

    a0 = RD16(rA + aoff[2] + cp16[1]);
    a1 = RD16(rA + aoff[3] + cp16[1]);
    if (st) {
      gld16(Bb + gboff[1] + kk, wS + 32768 + (1 * 512 + w * 64) * 16);
    }
    BARR();
    LGKM(0);
    SCHED0();
    __builtin_amdgcn_s_setprio(1);
    acc[2][0] = MFMA16(a0, b0, acc[2][0]);
    acc[2][1] = MFMA16(a0, b1, acc[2][1]);
    acc[2][2] = MFMA16(a0, b2, acc[2][2]);
    acc[2][3] = MFMA16(a0, b3, acc[2][3]);
    acc[3][0] = MFMA16(a1, b0, acc[3][0]);
    acc[3][1] = MFMA16(a1, b1, acc[3][1]);
    acc[3][2] = MFMA16(a1, b2, acc[3][2]);
    acc[3][3] = MFMA16(a1, b3, acc[3][3]);
    __builtin_amdgcn_s_setprio(0);

    s = (s + 1 == 3) ? 0 : s + 1;
  }

  const int bm0 = by * 256 + wr * 64;
  const int bn0 = bx * 128 + wc * 64;
  float* Cf = (float*)C;
  u16*   Ch = (u16*)C;
  #pragma unroll
  for (int mi = 0; mi < 4; ++mi) {
    #pragma unroll
    for (int ni = 0; ni < 4; ++ni) {
      const int col = bn0 + ni * 16 + l15;
      const int r0  = bm0 + mi * 16 + l4 * 4;
      float bv = 0.f;
      if (EPI == 0 || EPI == 4) bv = bias[col];
      #pragma unroll
      for (int r = 0; r < 4; ++r) {
        const size_t idx = (size_t)blockIdx.z * cstr + (size_t)(r0 + r) * ldc + col;
        const float v = acc[mi][ni][r];
        if      (EPI == 0) Ch[idx] = f2bf(v + bv);
        else if (EPI == 1) Cf[idx] = v * scale;
        else if (EPI == 2) Cf[idx] = v + add[idx];
        else if (EPI == 4) Cf[idx] = v + bv + add[idx];
        else if (EPI == 5) Ch[idx] = f2bf(v + bias[r0 + r]);
        else if (EPI == 6) Ch[idx] = f2bf(v * scale);
      }
    }
  }
}

// ---------------------------------------------------------------------------
__global__ __launch_bounds__(256) void ln_kernel(
    const float* __restrict__ x, const float* __restrict__ g,
    const float* __restrict__ be, u16* __restrict__ out)
{
  const int row = blockIdx.x;
  const int tid = threadIdx.x;
  const float4 v = ((const float4*)(x + (size_t)row * EMBED))[tid];
  float s  = v.x + v.y + v.z + v.w;
  float s2 = v.x * v.x + v.y * v.y + v.z * v.z + v.w * v.w;
  #pragma unroll
  for (int m = 1; m < 64; m <<= 1) { s += __shfl_xor(s, m); s2 += __shfl_xor(s2, m); }
  __shared__ float ls[4], ls2[4];
  const int w = tid >> 6;
  if ((tid & 63) == 0) { ls[w] = s; ls2[w] = s2; }
  __syncthreads();
  s  = ls[0] + ls[1] + ls[2] + ls[3];
  s2 = ls2[0] + ls2[1] + ls2[2] + ls2[3];
  const float mu   = s * (1.f / EMBED);
  const float var  = s2 * (1.f / EMBED) - mu * mu;
  const float rstd = rsqrtf(var + 1e-5f);
  const float4 gv = ((const float4*)g)[tid];
  const float4 bv = ((const float4*)be)[tid];
  ushort4 o;
  o.x = f2bf((v.x - mu) * rstd * gv.x + bv.x);
  o.y = f2bf((v.y - mu) * rstd * gv.y + bv.y);
  o.z = f2bf((v.z - mu) * rstd * gv.z + bv.z);
  o.w = f2bf((v.w - mu) * rstd * gv.w + bv.w);
  ((ushort4*)(out + (size_t)row * EMBED))[tid] = o;
}

// ---------------------------------------------------------------------------
__global__ __launch_bounds__(256) void softmax_bf16(
    const u16* __restrict__ S, u16* __restrict__ P)
{
  const int tid = threadIdx.x;
  const size_t base = ((size_t)blockIdx.y * SEQ + blockIdx.x) * SEQ;
  const ushort4* src = (const ushort4*)(S + base);
  const ushort4 ua = src[tid];
  const ushort4 ub = src[tid + 256];
  float a0 = bf2f(ua.x), a1 = bf2f(ua.y), a2 = bf2f(ua.z), a3 = bf2f(ua.w);
  float b0 = bf2f(ub.x), b1 = bf2f(ub.y), b2 = bf2f(ub.z), b3 = bf2f(ub.w);
  float m = fmaxf(fmaxf(fmaxf(a0, a1), fmaxf(a2, a3)),
                  fmaxf(fmaxf(b0, b1), fmaxf(b2, b3)));
  #pragma unroll
  for (int msk = 1; msk < 64; msk <<= 1) m = fmaxf(m, __shfl_xor(m, msk));
  __shared__ float red[8];
  const int w = tid >> 6;
  if ((tid & 63) == 0) red[w] = m;
  __syncthreads();
  m = fmaxf(fmaxf(red[0], red[1]), fmaxf(red[2], red[3]));
  a0 = __expf(a0 - m); a1 = __expf(a1 - m); a2 = __expf(a2 - m); a3 = __expf(a3 - m);
  b0 = __expf(b0 - m); b1 = __expf(b1 - m); b2 = __expf(b2 - m); b3 = __expf(b3 - m);
  float s = a0 + a1 + a2 + a3 + b0 + b1 + b2 + b3;
  #pragma unroll
  for (int msk = 1; msk < 64; msk <<= 1) s += __shfl_xor(s, msk);
  if ((tid & 63) == 0) red[4 + w] = s;
  __syncthreads();
  s = red[4] + red[5] + red[6] + red[7];
  const float inv = 1.0f / s;
  ushort4 oa, ob;
  oa.x = f2bf(a0 * inv); oa.y = f2bf(a1 * inv); oa.z = f2bf(a2 * inv); oa.w = f2bf(a3 * inv);
  ob.x = f2bf(b0 * inv); ob.y = f2bf(b1 * inv); ob.z = f2bf(b2 * inv); ob.w = f2bf(b3 * inv);
  ushort4* dst = (ushort4*)(P + base);
  dst[tid]       = oa;
  dst[tid + 256] = ob;
}

// ---------------------------------------------------------------------------
__global__ void transpose_cast3(const float* __restrict__ W0,
                                const float* __restrict__ W1_,
                                const float* __restrict__ W2_,
                                u16* __restrict__ Wt)
{
  __shared__ float t[32][33];
  const int z = blockIdx.z;
  const float* W = (z == 0) ? W0 : (z == 1) ? W1_ : W2_;
  u16* dst = Wt + (size_t)z * EMBED * EMBED;
  const int tx = threadIdx.x, ty = threadIdx.y;
  const int n0 = blockIdx.x * 32, k0 = blockIdx.y * 32;
  #pragma unroll
  for (int i = 0; i < 4; ++i)
    t[ty + i * 8][tx] = W[(size_t)(k0 + ty + i * 8) * EMBED + n0 + tx];
  __syncthreads();
  #pragma unroll
  for (int i = 0; i < 4; ++i)
    dst[(size_t)(n0 + ty + i * 8) * EMBED + k0 + tx] = f2bf(t[tx][ty + i * 8]);
}

__global__ void transpose_cast_f32(const float* __restrict__ W, u16* __restrict__ Wt,
                                   int K, int N)
{
  __shared__ float t[32][33];
  const int tx = threadIdx.x, ty = threadIdx.y;
  const int n0 = blockIdx.x * 32, k0 = blockIdx.y * 32;
  #pragma unroll
  for (int i = 0; i < 4; ++i)
    t[ty + i * 8][tx] = W[(size_t)(k0 + ty + i * 8) * N + n0 + tx];
  __syncthreads();
  #pragma unroll
  for (int i = 0; i < 4; ++i)
    Wt[(size_t)(n0 + ty + i * 8) * K + k0 + tx] = f2bf(t[tx][ty + i * 8]);
}

__global__ void concat_bias2(const float* __restrict__ a, const float* __restrict__ b,
                             float* __restrict__ o)
{
  const int i = blockIdx.x * 1024 + threadIdx.x;
  o[i] = (i < 1024) ? a[i] : b[i - 1024];
}

// ---------------------------------------------------------------------------
extern "C" void kernel_launch(void* const* d_in, const int* in_sizes, int n_in,
                              void* d_out, int out_size, void* d_ws, size_t ws_size,
                              hipStream_t stream)
{
  const float* x   = (const float*)d_in[0];
  const float* Wq  = (const float*)d_in[1];
  const float* bq  = (const float*)d_in[2];
  const float* Wk  = (const float*)d_in[3];
  const float* bk  = (const float*)d_in[4];
  const float* Wv  = (const float*)d_in[5];
  const float* bv  = (const float*)d_in[6];
  const float* W1  = (const float*)d_in[7];
  const float* b1  = (const float*)d_in[8];
  const float* W2  = (const float*)d_in[9];
  const float* b2  = (const float*)d_in[10];
  const float* g1  = (const float*)d_in[11];
  const float* be1 = (const float*)d_in[12];
  const float* g2  = (const float*)d_in[13];
  const float* be2 = (const float*)d_in[14];
  float* out = (float*)d_out;

  const size_t RD = (size_t)NB * SEQ * EMBED;

  char* base = (char*)d_ws;
  size_t o = 0;
  auto alloc = [&](size_t bytes) -> void* {
    o = (o + 255) & ~(size_t)255;
    void* p = base + o;
    o += bytes;
    return p;
  };

  u16*   wqkv3T = (u16*)alloc((size_t)3 * EMBED * EMBED * 2);
  u16*   w1T    = (u16*)alloc((size_t)HID * EMBED * 2);
  u16*   w2T    = (u16*)alloc((size_t)EMBED * HID * 2);
  float* bqk    = (float*)alloc(2048 * 4);
  u16*   h      = (u16*)alloc(RD * 2);
  u16*   QKb    = (u16*)alloc(RD * 2 * 2);                    // [8192][2048]
  u16*   Vt     = (u16*)alloc(RD * 2);                        // [4][1024][2048]
  float* x2     = (float*)alloc(RD * 4);

  const size_t need_batched = o + (size_t)NB * SEQ * SEQ * 4 + 1024;
  const int NZ = (ws_size >= need_batched) ? NB : 1;
  u16* Sb16 = (u16*)alloc((size_t)NZ * SEQ * SEQ * 2);
  u16* Pb   = (u16*)alloc((size_t)NZ * SEQ * SEQ * 2);
  u16* ff   = (NZ == NB) ? Sb16                                // 64MB alias (S,P dead)
                         : (u16*)alloc((size_t)NB * SEQ * HID * 2);

  const u16* wqkT = wqkv3T;                                    // [2048][1024]
  const u16* wvT  = wqkv3T + (size_t)2 * EMBED * EMBED;        // [1024][1024]

  const dim3 blk(512);
  const dim3 tblk(32, 8);

  transpose_cast3<<<dim3(32, 32, 3), tblk, 0, stream>>>(Wq, Wk, Wv, wqkv3T);
  transpose_cast_f32<<<dim3(HID / 32, EMBED / 32), tblk, 0, stream>>>(W1, w1T, EMBED, HID);
  transpose_cast_f32<<<dim3(EMBED / 32, HID / 32), tblk, 0, stream>>>(W2, w2T, HID, EMBED);
  concat_bias2<<<dim3(2), dim3(1024), 0, stream>>>(bq, bk, bqk);

  ln_kernel<<<dim3(NB * SEQ), dim3(256), 0, stream>>>(x, g1, be1, h);

  // QK projection: [8192][2048] on v3 (BN=256, 256 blocks = 1/CU exact)
  gemm256v3<0><<<dim3(2048 / 256, NB * SEQ / 256, 1), blk, 0, stream>>>(
      h, EMBED, 0LL, wqkT, EMBED, 0LL, QKb, 2048, 0LL, bqk, 1.f, EMBED);

  // V^T projection (direct): Vt[b][d][s] = sum_k wvT[d][k]*h[b,s,k] + bv[d]
  gemm8p<5><<<dim3(SEQ / 128, EMBED / 256, NB), blk, 0, stream>>>(
      wvT, EMBED, 0LL, h, EMBED, (long long)SEQ * EMBED,
      Vt, SEQ, (long long)EMBED * SEQ, bv, nullptr, 1.f, EMBED);

  // attention: scores (bf16 S, v3) -> softmax -> PV (+ residual into x2)
  for (int b = 0; b < NB; b += NZ) {
    const u16* Qp  = QKb + (size_t)b * SEQ * 2048;
    const u16* Kp  = Qp + 1024;
    const u16* Vtp = Vt + (size_t)b * EMBED * SEQ;
    float* x2p     = x2 + (size_t)b * SEQ * EMBED;
    const float* xp = x + (size_t)b * SEQ * EMBED;
    gemm256v3<6><<<dim3(SEQ / 256, SEQ / 256, NZ), blk, 0, stream>>>(
        Qp, 2048, (long long)SEQ * 2048, Kp, 2048, (long long)SEQ * 2048,
        Sb16, SEQ, (long long)SEQ * SEQ, nullptr, 0.03125f, EMBED);
    softmax_bf16<<<dim3(SEQ, NZ), dim3(256), 0, stream>>>(Sb16, Pb);
    gemm8p<2><<<dim3(EMBED / 128, SEQ / 256, NZ), blk, 0, stream>>>(
        Pb, SEQ, (long long)SEQ * SEQ, Vtp, SEQ, (long long)EMBED * SEQ,
        x2p, EMBED, (long long)SEQ * EMBED, nullptr, xp, 1.f, SEQ);
  }

  ln_kernel<<<dim3(NB * SEQ), dim3(256), 0, stream>>>(x2, g2, be2, h);

  // MLP: MLP1 on v3, MLP2 on gemm8p
  gemm256v3<3><<<dim3(HID / 256, NB * SEQ / 256, 1), blk, 0, stream>>>(
      h, EMBED, 0LL, w1T, EMBED, 0LL, ff, HID, 0LL, b1, 1.f, EMBED);
  gemm8p<4><<<dim3(EMBED / 128, NB * SEQ / 256, 1), blk, 0, stream>>>(
      ff, HID, 0LL, w2T, HID, 0LL, out, EMBED, 0LL, b2, x2, 1.f, HID);
}

// Round 9
// 319.512 us; speedup vs baseline: 1.0795x; 1.0076x over previous
//
#include <hip/hip_runtime.h>

#define EMBED 1024
#define HID   4096
#define NB    4
#define SEQ   2048

typedef __attribute__((ext_vector_type(8)))  __bf16 bf16x8;
typedef __attribute__((ext_vector_type(4)))  float  f32x4;
typedef __attribute__((ext_vector_type(4)))  int    i32x4;
typedef unsigned short u16;

__device__ __forceinline__ u16 f2bf(float f) {
  unsigned u = __float_as_uint(f);
  u += 0x7FFFu + ((u >> 16) & 1u);
  return (u16)(u >> 16);
}
__device__ __forceinline__ float bf2f(u16 u) {
  return __uint_as_float(((unsigned)u) << 16);
}

typedef const __attribute__((address_space(1))) unsigned int* gas_t;
typedef __attribute__((address_space(3))) unsigned int* las_t;
__device__ __forceinline__ void gld16(const void* g, void* l) {
  __builtin_amdgcn_global_load_lds((gas_t)g, (las_t)l, 16, 0, 0);
}

#define RD16(p)       __builtin_bit_cast(bf16x8, *(const i32x4*)(p))
#define MFMA16(a,b,c) __builtin_amdgcn_mfma_f32_16x16x32_bf16(a, b, c, 0, 0, 0)
#define SCHED0()      __builtin_amdgcn_sched_barrier(0)
#define BARR()        __builtin_amdgcn_s_barrier()
#define VMW(n)        asm volatile("s_waitcnt vmcnt(" #n ")" ::: "memory")

// ---------------------------------------------------------------------------
// 256x256 NT GEMM v3 (round-8 proven): one barrier per K-tile, no explicit
// lgkmcnt — compiler emits counted waits and interleaves drain under MFMAs.
// EPI: 0 bias->bf16 | 3 bias,relu->bf16 | 6 *scale->bf16
// ---------------------------------------------------------------------------
template<int EPI>
__global__ __launch_bounds__(512, 2) void gemm256v3(
    const u16* __restrict__ A, int lda, long long astr,
    const u16* __restrict__ B, int ldb, long long bstr,
    void* __restrict__ C, int ldc, long long cstr,
    const float* __restrict__ bias,
    float scale, int Kdim)
{
  __shared__ char lds[131072];   // buf b: A at b*65536, B at b*65536+32768

  const int tid  = threadIdx.x;
  const int lane = tid & 63;
  const int w    = tid >> 6;
  const int wr   = w >> 2, wc = w & 3;    // 2x4 waves -> 128x64 per wave
  const int l15  = lane & 15, l4 = lane >> 4;

  const int gx   = gridDim.x;
  const int nwg  = gx * gridDim.y;
  const int orig = blockIdx.y * gx + blockIdx.x;
  const int t    = ((nwg & 7) == 0) ? ((orig & 7) * (nwg >> 3) + (orig >> 3)) : orig;
  const int bx   = t % gx, by = t / gx;

  const u16* Ab = A + (size_t)blockIdx.z * astr + (size_t)by * 256 * lda;
  const u16* Bb = B + (size_t)blockIdx.z * bstr + (size_t)bx * 256 * ldb;

  const int    srow = tid >> 3;
  const size_t sa   = (size_t)srow * lda + (size_t)(((tid & 7) ^ (srow & 7)) * 8);
  const size_t sb   = (size_t)srow * ldb + (size_t)(((tid & 7) ^ (srow & 7)) * 8);
  const int    ldst = tid * 16;

  auto stA = [&](int buf, int q, int kk) {
    gld16(Ab + (size_t)(q * 64) * lda + kk + sa, lds + buf * 65536 + q * 8192 + ldst);
  };
  auto stB = [&](int buf, int i, int kk) {
    gld16(Bb + (size_t)(i * 64) * ldb + kk + sb, lds + buf * 65536 + 32768 + i * 8192 + ldst);
  };

  const int arow = (wr * 128 + l15) * 128;
  const int brow = 32768 + (wc * 64 + l15) * 128;
  const int cp0  = ((0 + l4) ^ (l15 & 7)) * 16;
  const int cp1  = ((4 + l4) ^ (l15 & 7)) * 16;

  f32x4 acc[8][4] = {};
  const int NT = Kdim >> 6;

  stB(0, 0, 0); stB(0, 1, 0); stB(0, 2, 0); stB(0, 3, 0);
  stA(0, 0, 0); stA(0, 1, 0); stA(0, 2, 0); stA(0, 3, 0);

  for (int T = 0; T < NT; ++T) {
    const char* LB = lds + (T & 1) * 65536;
    VMW(0);
    SCHED0();
    BARR();
    SCHED0();

    if (T + 1 < NT) {
      const int b = (T & 1) ^ 1, kk = (T + 1) * 64;
      stB(b, 0, kk); stB(b, 1, kk); stB(b, 2, kk); stB(b, 3, kk);
      stA(b, 0, kk); stA(b, 1, kk); stA(b, 2, kk); stA(b, 3, kk);
    }

    bf16x8 b0 = RD16(LB + brow + 0 * 2048 + cp0);
    bf16x8 b1 = RD16(LB + brow + 1 * 2048 + cp0);
    bf16x8 b2 = RD16(LB + brow + 2 * 2048 + cp0);
    bf16x8 b3 = RD16(LB + brow + 3 * 2048 + cp0);
    bf16x8 b4 = RD16(LB + brow + 0 * 2048 + cp1);
    bf16x8 b5 = RD16(LB + brow + 1 * 2048 + cp1);
    bf16x8 b6 = RD16(LB + brow + 2 * 2048 + cp1);
    bf16x8 b7 = RD16(LB + brow + 3 * 2048 + cp1);

#define AQ(MP, x0, x1, x2, x3) \
    bf16x8 x0 = RD16(LB + arow + (MP) * 4096 + cp0); \
    bf16x8 x1 = RD16(LB + arow + (MP) * 4096 + cp1); \
    bf16x8 x2 = RD16(LB + arow + (MP) * 4096 + 2048 + cp0); \
    bf16x8 x3 = RD16(LB + arow + (MP) * 4096 + 2048 + cp1);

#define MQ(MP, x0, x1, x2, x3) \
    acc[2*(MP)  ][0] = MFMA16(x0, b0, acc[2*(MP)  ][0]); \
    acc[2*(MP)  ][1] = MFMA16(x0, b1, acc[2*(MP)  ][1]); \
    acc[2*(MP)  ][2] = MFMA16(x0, b2, acc[2*(MP)  ][2]); \
    acc[2*(MP)  ][3] = MFMA16(x0, b3, acc[2*(MP)  ][3]); \
    acc[2*(MP)+1][0] = MFMA16(x2, b0, acc[2*(MP)+1][0]); \
    acc[2*(MP)+1][1] = MFMA16(x2, b1, acc[2*(MP)+1][1]); \
    acc[2*(MP)+1][2] = MFMA16(x2, b2, acc[2*(MP)+1][2]); \
    acc[2*(MP)+1][3] = MFMA16(x2, b3, acc[2*(MP)+1][3]); \
    acc[2*(MP)  ][0] = MFMA16(x1, b4, acc[2*(MP)  ][0]); \
    acc[2*(MP)  ][1] = MFMA16(x1, b5, acc[2*(MP)  ][1]); \
    acc[2*(MP)  ][2] = MFMA16(x1, b6, acc[2*(MP)  ][2]); \
    acc[2*(MP)  ][3] = MFMA16(x1, b7, acc[2*(MP)  ][3]); \
    acc[2*(MP)+1][0] = MFMA16(x3, b4, acc[2*(MP)+1][0]); \
    acc[2*(MP)+1][1] = MFMA16(x3, b5, acc[2*(MP)+1][1]); \
    acc[2*(MP)+1][2] = MFMA16(x3, b6, acc[2*(MP)+1][2]); \
    acc[2*(MP)+1][3] = MFMA16(x3, b7, acc[2*(MP)+1][3]);

    AQ(0, a00, a01, a02, a03)
    AQ(1, a10, a11, a12, a13)
    MQ(0, a00, a01, a02, a03)
    AQ(2, a20, a21, a22, a23)
    MQ(1, a10, a11, a12, a13)
    AQ(3, a30, a31, a32, a33)
    MQ(2, a20, a21, a22, a23)
    MQ(3, a30, a31, a32, a33)
#undef AQ
#undef MQ
  }

  const int bm0 = by * 256 + wr * 128;
  const int bn0 = bx * 256 + wc * 64;
  u16* Ch = (u16*)C;
  #pragma unroll
  for (int mi = 0; mi < 8; ++mi) {
    #pragma unroll
    for (int ni = 0; ni < 4; ++ni) {
      const int col = bn0 + ni * 16 + l15;
      const int r0  = bm0 + mi * 16 + l4 * 4;
      float bv = 0.f;
      if (EPI == 0 || EPI == 3) bv = bias[col];
      #pragma unroll
      for (int r = 0; r < 4; ++r) {
        const size_t idx = (size_t)blockIdx.z * cstr + (size_t)(r0 + r) * ldc + col;
        const float v = acc[mi][ni][r];
        if      (EPI == 0) Ch[idx] = f2bf(v + bv);
        else if (EPI == 3) Ch[idx] = f2bf(fmaxf(v + bv, 0.f));
        else if (EPI == 6) Ch[idx] = f2bf(v * scale);
      }
    }
  }
}

// ---------------------------------------------------------------------------
// 256x128 NT GEMM v3: same one-barrier compiler-scheduled structure.
// 2 bufs x 48KB (A 32KB + B 16KB), stage lead = 1 tile (6 units).
// EPI: 5 row-bias->bf16 (V^T) | 7 +add_f32->bf16 (PV -> x2 residual)
//      8 col-bias,+add_bf16->f32 (MLP2 -> out)
// ---------------------------------------------------------------------------
template<int EPI>
__global__ __launch_bounds__(512, 2) void gemm128v3(
    const u16* __restrict__ A, int lda, long long astr,
    const u16* __restrict__ B, int ldb, long long bstr,
    void* __restrict__ C, int ldc, long long cstr,
    const float* __restrict__ bias,
    const void* __restrict__ add,
    float scale, int Kdim)
{
  __shared__ char lds[98304];    // buf b: A at b*49152, B at b*49152+32768

  const int tid  = threadIdx.x;
  const int lane = tid & 63;
  const int w    = tid >> 6;
  const int wr   = w >> 1, wc = w & 1;    // 4x2 waves -> 64x64 per wave
  const int l15  = lane & 15, l4 = lane >> 4;

  const int gx   = gridDim.x;
  const int nwg  = gx * gridDim.y;
  const int orig = blockIdx.y * gx + blockIdx.x;
  const int t    = ((nwg & 7) == 0) ? ((orig & 7) * (nwg >> 3) + (orig >> 3)) : orig;
  const int bx   = t % gx, by = t / gx;

  const u16* Ab = A + (size_t)blockIdx.z * astr + (size_t)by * 256 * lda;
  const u16* Bb = B + (size_t)blockIdx.z * bstr + (size_t)bx * 128 * ldb;

  size_t gaoff[4], gboff[2];
  #pragma unroll
  for (int i = 0; i < 4; ++i) {
    const int idx = i * 512 + tid, row = idx >> 3, gc = (idx & 7) ^ (row & 7);
    gaoff[i] = (size_t)row * lda + gc * 8;
  }
  #pragma unroll
  for (int j = 0; j < 2; ++j) {
    const int idx = j * 512 + tid, row = idx >> 3, gc = (idx & 7) ^ (row & 7);
    gboff[j] = (size_t)row * ldb + gc * 8;
  }

  auto stage = [&](char* SB, int kk) {
    #pragma unroll
    for (int i = 0; i < 4; ++i) gld16(Ab + gaoff[i] + kk, SB + (i * 512 + w * 64) * 16);
    #pragma unroll
    for (int j = 0; j < 2; ++j) gld16(Bb + gboff[j] + kk, SB + 32768 + (j * 512 + w * 64) * 16);
  };

  int aoff[4], boff[4];
  #pragma unroll
  for (int m = 0; m < 4; ++m) aoff[m] = (wr * 64 + m * 16 + l15) * 128;
  #pragma unroll
  for (int n = 0; n < 4; ++n) boff[n] = 32768 + (wc * 64 + n * 16 + l15) * 128;
  const int cp0 = ((0 + l4) ^ (l15 & 7)) * 16;
  const int cp1 = ((4 + l4) ^ (l15 & 7)) * 16;

  f32x4 acc[4][4] = {};
  const int NT = Kdim >> 6;

  stage(lds, 0);

  for (int T = 0; T < NT; ++T) {
    const char* LB = lds + (T & 1) * 49152;
    VMW(0);
    SCHED0();
    BARR();
    SCHED0();

    if (T + 1 < NT) stage(lds + ((T & 1) ^ 1) * 49152, (T + 1) * 64);

    bf16x8 b00 = RD16(LB + boff[0] + cp0);
    bf16x8 b01 = RD16(LB + boff[1] + cp0);
    bf16x8 b02 = RD16(LB + boff[2] + cp0);
    bf16x8 b03 = RD16(LB + boff[3] + cp0);
    bf16x8 b10 = RD16(LB + boff[0] + cp1);
    bf16x8 b11 = RD16(LB + boff[1] + cp1);
    bf16x8 b12 = RD16(LB + boff[2] + cp1);
    bf16x8 b13 = RD16(LB + boff[3] + cp1);
    bf16x8 a00 = RD16(LB + aoff[0] + cp0);
    bf16x8 a10 = RD16(LB + aoff[1] + cp0);
    bf16x8 a20 = RD16(LB + aoff[2] + cp0);
    bf16x8 a30 = RD16(LB + aoff[3] + cp0);
    bf16x8 a01 = RD16(LB + aoff[0] + cp1);
    bf16x8 a11 = RD16(LB + aoff[1] + cp1);
    bf16x8 a21 = RD16(LB + aoff[2] + cp1);
    bf16x8 a31 = RD16(LB + aoff[3] + cp1);

    acc[0][0] = MFMA16(a00, b00, acc[0][0]);
    acc[0][1] = MFMA16(a00, b01, acc[0][1]);
    acc[0][2] = MFMA16(a00, b02, acc[0][2]);
    acc[0][3] = MFMA16(a00, b03, acc[0][3]);
    acc[1][0] = MFMA16(a10, b00, acc[1][0]);
    acc[1][1] = MFMA16(a10, b01, acc[1][1]);
    acc[1][2] = MFMA16(a10, b02, acc[1][2]);
    acc[1][3] = MFMA16(a10, b03, acc[1][3]);
    acc[2][0] = MFMA16(a20, b00, acc[2][0]);
    acc[2][1] = MFMA16(a20, b01, acc[2][1]);
    acc[2][2] = MFMA16(a20, b02, acc[2][2]);
    acc[2][3] = MFMA16(a20, b03, acc[2][3]);
    acc[3][0] = MFMA16(a30, b00, acc[3][0]);
    acc[3][1] = MFMA16(a30, b01, acc[3][1]);
    acc[3][2] = MFMA16(a30, b02, acc[3][2]);
    acc[3][3] = MFMA16(a30, b03, acc[3][3]);
    acc[0][0] = MFMA16(a01, b10, acc[0][0]);
    acc[0][1] = MFMA16(a01, b11, acc[0][1]);
    acc[0][2] = MFMA16(a01, b12, acc[0][2]);
    acc[0][3] = MFMA16(a01, b13, acc[0][3]);
    acc[1][0] = MFMA16(a11, b10, acc[1][0]);
    acc[1][1] = MFMA16(a11, b11, acc[1][1]);
    acc[1][2] = MFMA16(a11, b12, acc[1][2]);
    acc[1][3] = MFMA16(a11, b13, acc[1][3]);
    acc[2][0] = MFMA16(a21, b10, acc[2][0]);
    acc[2][1] = MFMA16(a21, b11, acc[2][1]);
    acc[2][2] = MFMA16(a21, b12, acc[2][2]);
    acc[2][3] = MFMA16(a21, b13, acc[2][3]);
    acc[3][0] = MFMA16(a31, b10, acc[3][0]);
    acc[3][1] = MFMA16(a31, b11, acc[3][1]);
    acc[3][2] = MFMA16(a31, b12, acc[3][2]);
    acc[3][3] = MFMA16(a31, b13, acc[3][3]);
  }

  const int bm0 = by * 256 + wr * 64;
  const int bn0 = bx * 128 + wc * 64;
  float* Cf = (float*)C;
  u16*   Ch = (u16*)C;
  const float* addf = (const float*)add;
  const u16*   addh = (const u16*)add;
  #pragma unroll
  for (int mi = 0; mi < 4; ++mi) {
    #pragma unroll
    for (int ni = 0; ni < 4; ++ni) {
      const int col = bn0 + ni * 16 + l15;
      const int r0  = bm0 + mi * 16 + l4 * 4;
      float bv = 0.f;
      if (EPI == 8) bv = bias[col];
      #pragma unroll
      for (int r = 0; r < 4; ++r) {
        const size_t idx = (size_t)blockIdx.z * cstr + (size_t)(r0 + r) * ldc + col;
        const float v = acc[mi][ni][r];
        if      (EPI == 5) Ch[idx] = f2bf(v + bias[r0 + r]);
        else if (EPI == 7) Ch[idx] = f2bf(v + addf[idx]);
        else if (EPI == 8) Cf[idx] = v + bv + bf2f(addh[idx]);
      }
    }
  }
}

// ---------------------------------------------------------------------------
// LayerNorm, f32 input -> bf16 out
// ---------------------------------------------------------------------------
__global__ __launch_bounds__(256) void ln_kernel(
    const float* __restrict__ x, const float* __restrict__ g,
    const float* __restrict__ be, u16* __restrict__ out)
{
  const int row = blockIdx.x;
  const int tid = threadIdx.x;
  const float4 v = ((const float4*)(x + (size_t)row * EMBED))[tid];
  float s  = v.x + v.y + v.z + v.w;
  float s2 = v.x * v.x + v.y * v.y + v.z * v.z + v.w * v.w;
  #pragma unroll
  for (int m = 1; m < 64; m <<= 1) { s += __shfl_xor(s, m); s2 += __shfl_xor(s2, m); }
  __shared__ float ls[4], ls2[4];
  const int w = tid >> 6;
  if ((tid & 63) == 0) { ls[w] = s; ls2[w] = s2; }
  __syncthreads();
  s  = ls[0] + ls[1] + ls[2] + ls[3];
  s2 = ls2[0] + ls2[1] + ls2[2] + ls2[3];
  const float mu   = s * (1.f / EMBED);
  const float var  = s2 * (1.f / EMBED) - mu * mu;
  const float rstd = rsqrtf(var + 1e-5f);
  const float4 gv = ((const float4*)g)[tid];
  const float4 bv = ((const float4*)be)[tid];
  ushort4 o;
  o.x = f2bf((v.x - mu) * rstd * gv.x + bv.x);
  o.y = f2bf((v.y - mu) * rstd * gv.y + bv.y);
  o.z = f2bf((v.z - mu) * rstd * gv.z + bv.z);
  o.w = f2bf((v.w - mu) * rstd * gv.w + bv.w);
  ((ushort4*)(out + (size_t)row * EMBED))[tid] = o;
}

// LayerNorm, bf16 input -> bf16 out (for x2 residual path)
__global__ __launch_bounds__(256) void ln_bf16(
    const u16* __restrict__ x, const float* __restrict__ g,
    const float* __restrict__ be, u16* __restrict__ out)
{
  const int row = blockIdx.x;
  const int tid = threadIdx.x;
  const ushort4 u = ((const ushort4*)(x + (size_t)row * EMBED))[tid];
  float v0 = bf2f(u.x), v1 = bf2f(u.y), v2 = bf2f(u.z), v3 = bf2f(u.w);
  float s  = v0 + v1 + v2 + v3;
  float s2 = v0 * v0 + v1 * v1 + v2 * v2 + v3 * v3;
  #pragma unroll
  for (int m = 1; m < 64; m <<= 1) { s += __shfl_xor(s, m); s2 += __shfl_xor(s2, m); }
  __shared__ float ls[4], ls2[4];
  const int w = tid >> 6;
  if ((tid & 63) == 0) { ls[w] = s; ls2[w] = s2; }
  __syncthreads();
  s  = ls[0] + ls[1] + ls[2] + ls[3];
  s2 = ls2[0] + ls2[1] + ls2[2] + ls2[3];
  const float mu   = s * (1.f / EMBED);
  const float var  = s2 * (1.f / EMBED) - mu * mu;
  const float rstd = rsqrtf(var + 1e-5f);
  const float4 gv = ((const float4*)g)[tid];
  const float4 bv = ((const float4*)be)[tid];
  ushort4 o;
  o.x = f2bf((v0 - mu) * rstd * gv.x + bv.x);
  o.y = f2bf((v1 - mu) * rstd * gv.y + bv.y);
  o.z = f2bf((v2 - mu) * rstd * gv.z + bv.z);
  o.w = f2bf((v3 - mu) * rstd * gv.w + bv.w);
  ((ushort4*)(out + (size_t)row * EMBED))[tid] = o;
}

// ---------------------------------------------------------------------------
__global__ __launch_bounds__(256) void softmax_bf16(
    const u16* __restrict__ S, u16* __restrict__ P)
{
  const int tid = threadIdx.x;
  const size_t base = ((size_t)blockIdx.y * SEQ + blockIdx.x) * SEQ;
  const ushort4* src = (const ushort4*)(S + base);
  const ushort4 ua = src[tid];
  const ushort4 ub = src[tid + 256];
  float a0 = bf2f(ua.x), a1 = bf2f(ua.y), a2 = bf2f(ua.z), a3 = bf2f(ua.w);
  float b0 = bf2f(ub.x), b1 = bf2f(ub.y), b2 = bf2f(ub.z), b3 = bf2f(ub.w);
  float m = fmaxf(fmaxf(fmaxf(a0, a1), fmaxf(a2, a3)),
                  fmaxf(fmaxf(b0, b1), fmaxf(b2, b3)));
  #pragma unroll
  for (int msk = 1; msk < 64; msk <<= 1) m = fmaxf(m, __shfl_xor(m, msk));
  __shared__ float red[8];
  const int w = tid >> 6;
  if ((tid & 63) == 0) red[w] = m;
  __syncthreads();
  m = fmaxf(fmaxf(red[0], red[1]), fmaxf(red[2], red[3]));
  a0 = __expf(a0 - m); a1 = __expf(a1 - m); a2 = __expf(a2 - m); a3 = __expf(a3 - m);
  b0 = __expf(b0 - m); b1 = __expf(b1 - m); b2 = __expf(b2 - m); b3 = __expf(b3 - m);
  float s = a0 + a1 + a2 + a3 + b0 + b1 + b2 + b3;
  #pragma unroll
  for (int msk = 1; msk < 64; msk <<= 1) s += __shfl_xor(s, msk);
  if ((tid & 63) == 0) red[4 + w] = s;
  __syncthreads();
  s = red[4] + red[5] + red[6] + red[7];
  const float inv = 1.0f / s;
  ushort4 oa, ob;
  oa.x = f2bf(a0 * inv); oa.y = f2bf(a1 * inv); oa.z = f2bf(a2 * inv); oa.w = f2bf(a3 * inv);
  ob.x = f2bf(b0 * inv); ob.y = f2bf(b1 * inv); ob.z = f2bf(b2 * inv); ob.w = f2bf(b3 * inv);
  ushort4* dst = (ushort4*)(P + base);
  dst[tid]       = oa;
  dst[tid + 256] = ob;
}

// ---------------------------------------------------------------------------
__global__ void transpose_cast3(const float* __restrict__ W0,
                                const float* __restrict__ W1_,
                                const float* __restrict__ W2_,
                                u16* __restrict__ Wt)
{
  __shared__ float t[32][33];
  const int z = blockIdx.z;
  const float* W = (z == 0) ? W0 : (z == 1) ? W1_ : W2_;
  u16* dst = Wt + (size_t)z * EMBED * EMBED;
  const int tx = threadIdx.x, ty = threadIdx.y;
  const int n0 = blockIdx.x * 32, k0 = blockIdx.y * 32;
  #pragma unroll
  for (int i = 0; i < 4; ++i)
    t[ty + i * 8][tx] = W[(size_t)(k0 + ty + i * 8) * EMBED + n0 + tx];
  __syncthreads();
  #pragma unroll
  for (int i = 0; i < 4; ++i)
    dst[(size_t)(n0 + ty + i * 8) * EMBED + k0 + tx] = f2bf(t[tx][ty + i * 8]);
}

__global__ void transpose_cast_f32(const float* __restrict__ W, u16* __restrict__ Wt,
                                   int K, int N)
{
  __shared__ float t[32][33];
  const int tx = threadIdx.x, ty = threadIdx.y;
  const int n0 = blockIdx.x * 32, k0 = blockIdx.y * 32;
  #pragma unroll
  for (int i = 0; i < 4; ++i)
    t[ty + i * 8][tx] = W[(size_t)(k0 + ty + i * 8) * N + n0 + tx];
  __syncthreads();
  #pragma unroll
  for (int i = 0; i < 4; ++i)
    Wt[(size_t)(n0 + ty + i * 8) * K + k0 + tx] = f2bf(t[tx][ty + i * 8]);
}

__global__ void concat_bias2(const float* __restrict__ a, const float* __restrict__ b,
                             float* __restrict__ o)
{
  const int i = blockIdx.x * 1024 + threadIdx.x;
  o[i] = (i < 1024) ? a[i] : b[i - 1024];
}

// ---------------------------------------------------------------------------
extern "C" void kernel_launch(void* const* d_in, const int* in_sizes, int n_in,
                              void* d_out, int out_size, void* d_ws, size_t ws_size,
                              hipStream_t stream)
{
  const float* x   = (const float*)d_in[0];
  const float* Wq  = (const float*)d_in[1];
  const float* bq  = (const float*)d_in[2];
  const float* Wk  = (const float*)d_in[3];
  const float* bk  = (const float*)d_in[4];
  const float* Wv  = (const float*)d_in[5];
  const float* bv  = (const float*)d_in[6];
  const float* W1  = (const float*)d_in[7];
  const float* b1  = (const float*)d_in[8];
  const float* W2  = (const float*)d_in[9];
  const float* b2  = (const float*)d_in[10];
  const float* g1  = (const float*)d_in[11];
  const float* be1 = (const float*)d_in[12];
  const float* g2  = (const float*)d_in[13];
  const float* be2 = (const float*)d_in[14];
  float* out = (float*)d_out;

  const size_t RD = (size_t)NB * SEQ * EMBED;

  char* base = (char*)d_ws;
  size_t o = 0;
  auto alloc = [&](size_t bytes) -> void* {
    o = (o + 255) & ~(size_t)255;
    void* p = base + o;
    o += bytes;
    return p;
  };

  u16*   wqkv3T = (u16*)alloc((size_t)3 * EMBED * EMBED * 2);
  u16*   w1T    = (u16*)alloc((size_t)HID * EMBED * 2);
  u16*   w2T    = (u16*)alloc((size_t)EMBED * HID * 2);
  float* bqk    = (float*)alloc(2048 * 4);
  u16*   h      = (u16*)alloc(RD * 2);
  u16*   QKb    = (u16*)alloc(RD * 2 * 2);                    // [8192][2048]
  u16*   Vt     = (u16*)alloc(RD * 2);                        // [4][1024][2048]
  u16*   x2     = (u16*)alloc(RD * 2);                        // bf16 residual

  const size_t need_batched = o + (size_t)NB * SEQ * SEQ * 4 + 1024;
  const int NZ = (ws_size >= need_batched) ? NB : 1;
  u16* Sb16 = (u16*)alloc((size_t)NZ * SEQ * SEQ * 2);
  u16* Pb   = (u16*)alloc((size_t)NZ * SEQ * SEQ * 2);
  u16* ff   = (NZ == NB) ? Sb16                                // 64MB alias (S,P dead)
                         : (u16*)alloc((size_t)NB * SEQ * HID * 2);

  const u16* wqkT = wqkv3T;                                    // [2048][1024]
  const u16* wvT  = wqkv3T + (size_t)2 * EMBED * EMBED;        // [1024][1024]

  const dim3 blk(512);
  const dim3 tblk(32, 8);

  transpose_cast3<<<dim3(32, 32, 3), tblk, 0, stream>>>(Wq, Wk, Wv, wqkv3T);
  transpose_cast_f32<<<dim3(HID / 32, EMBED / 32), tblk, 0, stream>>>(W1, w1T, EMBED, HID);
  transpose_cast_f32<<<dim3(EMBED / 32, HID / 32), tblk, 0, stream>>>(W2, w2T, HID, EMBED);
  concat_bias2<<<dim3(2), dim3(1024), 0, stream>>>(bq, bk, bqk);

  ln_kernel<<<dim3(NB * SEQ), dim3(256), 0, stream>>>(x, g1, be1, h);

  // QK projection: [8192][2048]
  gemm256v3<0><<<dim3(2048 / 256, NB * SEQ / 256, 1), blk, 0, stream>>>(
      h, EMBED, 0LL, wqkT, EMBED, 0LL, QKb, 2048, 0LL, bqk, 1.f, EMBED);

  // V^T projection (direct): Vt[b][d][s] = sum_k wvT[d][k]*h[b,s,k] + bv[d]
  gemm128v3<5><<<dim3(SEQ / 128, EMBED / 256, NB), blk, 0, stream>>>(
      wvT, EMBED, 0LL, h, EMBED, (long long)SEQ * EMBED,
      Vt, SEQ, (long long)EMBED * SEQ, bv, nullptr, 1.f, EMBED);

  // attention: scores (bf16) -> softmax -> PV (+ residual -> bf16 x2)
  for (int b = 0; b < NB; b += NZ) {
    const u16* Qp  = QKb + (size_t)b * SEQ * 2048;
    const u16* Kp  = Qp + 1024;
    const u16* Vtp = Vt + (size_t)b * EMBED * SEQ;
    u16* x2p       = x2 + (size_t)b * SEQ * EMBED;
    const float* xp = x + (size_t)b * SEQ * EMBED;
    gemm256v3<6><<<dim3(SEQ / 256, SEQ / 256, NZ), blk, 0, stream>>>(
        Qp, 2048, (long long)SEQ * 2048, Kp, 2048, (long long)SEQ * 2048,
        Sb16, SEQ, (long long)SEQ * SEQ, nullptr, 0.03125f, EMBED);
    softmax_bf16<<<dim3(SEQ, NZ), dim3(256), 0, stream>>>(Sb16, Pb);
    gemm128v3<7><<<dim3(EMBED / 128, SEQ / 256, NZ), blk, 0, stream>>>(
        Pb, SEQ, (long long)SEQ * SEQ, Vtp, SEQ, (long long)EMBED * SEQ,
        x2p, EMBED, (long long)SEQ * EMBED, nullptr, xp, 1.f, SEQ);
  }

  // LN2 on bf16 residual
  ln_bf16<<<dim3(NB * SEQ), dim3(256), 0, stream>>>(x2, g2, be2, h);

  // MLP
  gemm256v3<3><<<dim3(HID / 256, NB * SEQ / 256, 1), blk, 0, stream>>>(
      h, EMBED, 0LL, w1T, EMBED, 0LL, ff, HID, 0LL, b1, 1.f, EMBED);
  gemm128v3<8><<<dim3(EMBED / 128, NB * SEQ / 256, 1), blk, 0, stream>>>(
      ff, HID, 0LL, w2T, HID, 0LL, out, EMBED, 0LL, b2, x2, 1.f, HID);
}

// Round 10
// 315.816 us; speedup vs baseline: 1.0921x; 1.0117x over previous
//
#include <hip/hip_runtime.h>

#define EMBED 1024
#define HID   4096
#define NB    4
#define SEQ   2048

typedef __attribute__((ext_vector_type(8)))  __bf16 bf16x8;
typedef __attribute__((ext_vector_type(4)))  float  f32x4;
typedef __attribute__((ext_vector_type(4)))  int    i32x4;
typedef unsigned short u16;

__device__ __forceinline__ u16 f2bf(float f) {
  unsigned u = __float_as_uint(f);
  u += 0x7FFFu + ((u >> 16) & 1u);
  return (u16)(u >> 16);
}
__device__ __forceinline__ float bf2f(u16 u) {
  return __uint_as_float(((unsigned)u) << 16);
}

typedef const __attribute__((address_space(1))) unsigned int* gas_t;
typedef __attribute__((address_space(3))) unsigned int* las_t;
__device__ __forceinline__ void gld16(const void* g, void* l) {
  __builtin_amdgcn_global_load_lds((gas_t)g, (las_t)l, 16, 0, 0);
}

#define RD16(p)       __builtin_bit_cast(bf16x8, *(const i32x4*)(p))
#define MFMA16(a,b,c) __builtin_amdgcn_mfma_f32_16x16x32_bf16(a, b, c, 0, 0, 0)
#define SCHED0()      __builtin_amdgcn_sched_barrier(0)
#define BARR()        __builtin_amdgcn_s_barrier()
#define VMW(n)        asm volatile("s_waitcnt vmcnt(" #n ")" ::: "memory")

// ---------------------------------------------------------------------------
// 256x256 NT GEMM v3 (round-8 proven, untouched): one barrier per K-tile,
// no explicit lgkmcnt — compiler emits counted waits.
// EPI: 0 bias->bf16 | 3 bias,relu->bf16 | 6 *scale->bf16
// ---------------------------------------------------------------------------
template<int EPI>
__global__ __launch_bounds__(512, 2) void gemm256v3(
    const u16* __restrict__ A, int lda, long long astr,
    const u16* __restrict__ B, int ldb, long long bstr,
    void* __restrict__ C, int ldc, long long cstr,
    const float* __restrict__ bias,
    float scale, int Kdim)
{
  __shared__ char lds[131072];   // buf b: A at b*65536, B at b*65536+32768

  const int tid  = threadIdx.x;
  const int lane = tid & 63;
  const int w    = tid >> 6;
  const int wr   = w >> 2, wc = w & 3;    // 2x4 waves -> 128x64 per wave
  const int l15  = lane & 15, l4 = lane >> 4;

  const int gx   = gridDim.x;
  const int nwg  = gx * gridDim.y;
  const int orig = blockIdx.y * gx + blockIdx.x;
  const int t    = ((nwg & 7) == 0) ? ((orig & 7) * (nwg >> 3) + (orig >> 3)) : orig;
  const int bx   = t % gx, by = t / gx;

  const u16* Ab = A + (size_t)blockIdx.z * astr + (size_t)by * 256 * lda;
  const u16* Bb = B + (size_t)blockIdx.z * bstr + (size_t)bx * 256 * ldb;

  const int    srow = tid >> 3;
  const size_t sa   = (size_t)srow * lda + (size_t)(((tid & 7) ^ (srow & 7)) * 8);
  const size_t sb   = (size_t)srow * ldb + (size_t)(((tid & 7) ^ (srow & 7)) * 8);
  const int    ldst = tid * 16;

  auto stA = [&](int buf, int q, int kk) {
    gld16(Ab + (size_t)(q * 64) * lda + kk + sa, lds + buf * 65536 + q * 8192 + ldst);
  };
  auto stB = [&](int buf, int i, int kk) {
    gld16(Bb + (size_t)(i * 64) * ldb + kk + sb, lds + buf * 65536 + 32768 + i * 8192 + ldst);
  };

  const int arow = (wr * 128 + l15) * 128;
  const int brow = 32768 + (wc * 64 + l15) * 128;
  const int cp0  = ((0 + l4) ^ (l15 & 7)) * 16;
  const int cp1  = ((4 + l4) ^ (l15 & 7)) * 16;

  f32x4 acc[8][4] = {};
  const int NT = Kdim >> 6;

  stB(0, 0, 0); stB(0, 1, 0); stB(0, 2, 0); stB(0, 3, 0);
  stA(0, 0, 0); stA(0, 1, 0); stA(0, 2, 0); stA(0, 3, 0);

  for (int T = 0; T < NT; ++T) {
    const char* LB = lds + (T & 1) * 65536;
    VMW(0);
    SCHED0();
    BARR();
    SCHED0();

    if (T + 1 < NT) {
      const int b = (T & 1) ^ 1, kk = (T + 1) * 64;
      stB(b, 0, kk); stB(b, 1, kk); stB(b, 2, kk); stB(b, 3, kk);
      stA(b, 0, kk); stA(b, 1, kk); stA(b, 2, kk); stA(b, 3, kk);
    }

    bf16x8 b0 = RD16(LB + brow + 0 * 2048 + cp0);
    bf16x8 b1 = RD16(LB + brow + 1 * 2048 + cp0);
    bf16x8 b2 = RD16(LB + brow + 2 * 2048 + cp0);
    bf16x8 b3 = RD16(LB + brow + 3 * 2048 + cp0);
    bf16x8 b4 = RD16(LB + brow + 0 * 2048 + cp1);
    bf16x8 b5 = RD16(LB + brow + 1 * 2048 + cp1);
    bf16x8 b6 = RD16(LB + brow + 2 * 2048 + cp1);
    bf16x8 b7 = RD16(LB + brow + 3 * 2048 + cp1);

#define AQ(MP, x0, x1, x2, x3) \
    bf16x8 x0 = RD16(LB + arow + (MP) * 4096 + cp0); \
    bf16x8 x1 = RD16(LB + arow + (MP) * 4096 + cp1); \
    bf16x8 x2 = RD16(LB + arow + (MP) * 4096 + 2048 + cp0); \
    bf16x8 x3 = RD16(LB + arow + (MP) * 4096 + 2048 + cp1);

#define MQ(MP, x0, x1, x2, x3) \
    acc[2*(MP)  ][0] = MFMA16(x0, b0, acc[2*(MP)  ][0]); \
    acc[2*(MP)  ][1] = MFMA16(x0, b1, acc[2*(MP)  ][1]); \
    acc[2*(MP)  ][2] = MFMA16(x0, b2, acc[2*(MP)  ][2]); \
    acc[2*(MP)  ][3] = MFMA16(x0, b3, acc[2*(MP)  ][3]); \
    acc[2*(MP)+1][0] = MFMA16(x2, b0, acc[2*(MP)+1][0]); \
    acc[2*(MP)+1][1] = MFMA16(x2, b1, acc[2*(MP)+1][1]); \
    acc[2*(MP)+1][2] = MFMA16(x2, b2, acc[2*(MP)+1][2]); \
    acc[2*(MP)+1][3] = MFMA16(x2, b3, acc[2*(MP)+1][3]); \
    acc[2*(MP)  ][0] = MFMA16(x1, b4, acc[2*(MP)  ][0]); \
    acc[2*(MP)  ][1] = MFMA16(x1, b5, acc[2*(MP)  ][1]); \
    acc[2*(MP)  ][2] = MFMA16(x1, b6, acc[2*(MP)  ][2]); \
    acc[2*(MP)  ][3] = MFMA16(x1, b7, acc[2*(MP)  ][3]); \
    acc[2*(MP)+1][0] = MFMA16(x3, b4, acc[2*(MP)+1][0]); \
    acc[2*(MP)+1][1] = MFMA16(x3, b5, acc[2*(MP)+1][1]); \
    acc[2*(MP)+1][2] = MFMA16(x3, b6, acc[2*(MP)+1][2]); \
    acc[2*(MP)+1][3] = MFMA16(x3, b7, acc[2*(MP)+1][3]);

    AQ(0, a00, a01, a02, a03)
    AQ(1, a10, a11, a12, a13)
    MQ(0, a00, a01, a02, a03)
    AQ(2, a20, a21, a22, a23)
    MQ(1, a10, a11, a12, a13)
    AQ(3, a30, a31, a32, a33)
    MQ(2, a20, a21, a22, a23)
    MQ(3, a30, a31, a32, a33)
#undef AQ
#undef MQ
  }

  const int bm0 = by * 256 + wr * 128;
  const int bn0 = bx * 256 + wc * 64;
  u16* Ch = (u16*)C;
  #pragma unroll
  for (int mi = 0; mi < 8; ++mi) {
    #pragma unroll
    for (int ni = 0; ni < 4; ++ni) {
      const int col = bn0 + ni * 16 + l15;
      const int r0  = bm0 + mi * 16 + l4 * 4;
      float bv = 0.f;
      if (EPI == 0 || EPI == 3) bv = bias[col];
      #pragma unroll
      for (int r = 0; r < 4; ++r) {
        const size_t idx = (size_t)blockIdx.z * cstr + (size_t)(r0 + r) * ldc + col;
        const float v = acc[mi][ni][r];
        if      (EPI == 0) Ch[idx] = f2bf(v + bv);
        else if (EPI == 3) Ch[idx] = f2bf(fmaxf(v + bv, 0.f));
        else if (EPI == 6) Ch[idx] = f2bf(v * scale);
      }
    }
  }
}

// ---------------------------------------------------------------------------
// 256x128 NT GEMM v3.1: fence-free v3 body + 3-slot stage-lead-2 ledger
// (gemm8p's proven FIFO: VMW(6) at tile top retires the current tile;
// stage target slot (T+2)%3 was fully read in tile T-1, whose ds_reads
// drained before this barrier).
// EPI: 5 row-bias->bf16 (V^T) | 7 +add_f32->bf16 (PV -> x2 residual)
//      8 col-bias,+add_bf16->f32 (MLP2 -> out)
// ---------------------------------------------------------------------------
template<int EPI>
__global__ __launch_bounds__(512, 2) void gemm128v3(
    const u16* __restrict__ A, int lda, long long astr,
    const u16* __restrict__ B, int ldb, long long bstr,
    void* __restrict__ C, int ldc, long long cstr,
    const float* __restrict__ bias,
    const void* __restrict__ add,
    float scale, int Kdim)
{
  __shared__ char lds[147456];   // 3 slots x 48KB (A 32KB + B 16KB)
  const int SLOT = 49152;

  const int tid  = threadIdx.x;
  const int lane = tid & 63;
  const int w    = tid >> 6;
  const int wr   = w >> 1, wc = w & 1;    // 4x2 waves -> 64x64 per wave
  const int l15  = lane & 15, l4 = lane >> 4;

  const int gx   = gridDim.x;
  const int nwg  = gx * gridDim.y;
  const int orig = blockIdx.y * gx + blockIdx.x;
  const int t    = ((nwg & 7) == 0) ? ((orig & 7) * (nwg >> 3) + (orig >> 3)) : orig;
  const int bx   = t % gx, by = t / gx;

  const u16* Ab = A + (size_t)blockIdx.z * astr + (size_t)by * 256 * lda;
  const u16* Bb = B + (size_t)blockIdx.z * bstr + (size_t)bx * 128 * ldb;

  size_t gaoff[4], gboff[2];
  #pragma unroll
  for (int i = 0; i < 4; ++i) {
    const int idx = i * 512 + tid, row = idx >> 3, gc = (idx & 7) ^ (row & 7);
    gaoff[i] = (size_t)row * lda + gc * 8;
  }
  #pragma unroll
  for (int j = 0; j < 2; ++j) {
    const int idx = j * 512 + tid, row = idx >> 3, gc = (idx & 7) ^ (row & 7);
    gboff[j] = (size_t)row * ldb + gc * 8;
  }

  auto stage = [&](char* SB, int kk) {
    #pragma unroll
    for (int i = 0; i < 4; ++i) gld16(Ab + gaoff[i] + kk, SB + (i * 512 + w * 64) * 16);
    #pragma unroll
    for (int j = 0; j < 2; ++j) gld16(Bb + gboff[j] + kk, SB + 32768 + (j * 512 + w * 64) * 16);
  };

  int aoff[4], boff[4];
  #pragma unroll
  for (int m = 0; m < 4; ++m) aoff[m] = (wr * 64 + m * 16 + l15) * 128;
  #pragma unroll
  for (int n = 0; n < 4; ++n) boff[n] = 32768 + (wc * 64 + n * 16 + l15) * 128;
  const int cp0 = ((0 + l4) ^ (l15 & 7)) * 16;
  const int cp1 = ((4 + l4) ^ (l15 & 7)) * 16;

  f32x4 acc[4][4] = {};
  const int NT = Kdim >> 6;

  // prologue: stage tiles 0 and 1 (FIFO: tile0's 6 units are oldest)
  stage(lds, 0);
  stage(lds + SLOT, 64);

  int sr = 0;
  for (int T = 0; T < NT; ++T) {
    const char* LB = lds + sr * SLOT;
    if (T == NT - 1) VMW(0);
    else             VMW(6);        // 12 outstanding -> retire tile T's 6
    SCHED0();
    BARR();
    SCHED0();

    if (T + 2 < NT) stage(lds + ((sr + 2 >= 3) ? sr - 1 : sr + 2) * SLOT, (T + 2) * 64);

    bf16x8 b00 = RD16(LB + boff[0] + cp0);
    bf16x8 b01 = RD16(LB + boff[1] + cp0);
    bf16x8 b02 = RD16(LB + boff[2] + cp0);
    bf16x8 b03 = RD16(LB + boff[3] + cp0);
    bf16x8 b10 = RD16(LB + boff[0] + cp1);
    bf16x8 b11 = RD16(LB + boff[1] + cp1);
    bf16x8 b12 = RD16(LB + boff[2] + cp1);
    bf16x8 b13 = RD16(LB + boff[3] + cp1);
    bf16x8 a00 = RD16(LB + aoff[0] + cp0);
    bf16x8 a10 = RD16(LB + aoff[1] + cp0);
    bf16x8 a20 = RD16(LB + aoff[2] + cp0);
    bf16x8 a30 = RD16(LB + aoff[3] + cp0);
    bf16x8 a01 = RD16(LB + aoff[0] + cp1);
    bf16x8 a11 = RD16(LB + aoff[1] + cp1);
    bf16x8 a21 = RD16(LB + aoff[2] + cp1);
    bf16x8 a31 = RD16(LB + aoff[3] + cp1);

    acc[0][0] = MFMA16(a00, b00, acc[0][0]);
    acc[0][1] = MFMA16(a00, b01, acc[0][1]);
    acc[0][2] = MFMA16(a00, b02, acc[0][2]);
    acc[0][3] = MFMA16(a00, b03, acc[0][3]);
    acc[1][0] = MFMA16(a10, b00, acc[1][0]);
    acc[1][1] = MFMA16(a10, b01, acc[1][1]);
    acc[1][2] = MFMA16(a10, b02, acc[1][2]);
    acc[1][3] = MFMA16(a10, b03, acc[1][3]);
    acc[2][0] = MFMA16(a20, b00, acc[2][0]);
    acc[2][1] = MFMA16(a20, b01, acc[2][1]);
    acc[2][2] = MFMA16(a20, b02, acc[2][2]);
    acc[2][3] = MFMA16(a20, b03, acc[2][3]);
    acc[3][0] = MFMA16(a30, b00, acc[3][0]);
    acc[3][1] = MFMA16(a30, b01, acc[3][1]);
    acc[3][2] = MFMA16(a30, b02, acc[3][2]);
    acc[3][3] = MFMA16(a30, b03, acc[3][3]);
    acc[0][0] = MFMA16(a01, b10, acc[0][0]);
    acc[0][1] = MFMA16(a01, b11, acc[0][1]);
    acc[0][2] = MFMA16(a01, b12, acc[0][2]);
    acc[0][3] = MFMA16(a01, b13, acc[0][3]);
    acc[1][0] = MFMA16(a11, b10, acc[1][0]);
    acc[1][1] = MFMA16(a11, b11, acc[1][1]);
    acc[1][2] = MFMA16(a11, b12, acc[1][2]);
    acc[1][3] = MFMA16(a11, b13, acc[1][3]);
    acc[2][0] = MFMA16(a21, b10, acc[2][0]);
    acc[2][1] = MFMA16(a21, b11, acc[2][1]);
    acc[2][2] = MFMA16(a21, b12, acc[2][2]);
    acc[2][3] = MFMA16(a21, b13, acc[2][3]);
    acc[3][0] = MFMA16(a31, b10, acc[3][0]);
    acc[3][1] = MFMA16(a31, b11, acc[3][1]);
    acc[3][2] = MFMA16(a31, b12, acc[3][2]);
    acc[3][3] = MFMA16(a31, b13, acc[3][3]);

    sr = (sr + 1 == 3) ? 0 : sr + 1;
  }

  const int bm0 = by * 256 + wr * 64;
  const int bn0 = bx * 128 + wc * 64;
  float* Cf = (float*)C;
  u16*   Ch = (u16*)C;
  const float* addf = (const float*)add;
  const u16*   addh = (const u16*)add;
  #pragma unroll
  for (int mi = 0; mi < 4; ++mi) {
    #pragma unroll
    for (int ni = 0; ni < 4; ++ni) {
      const int col = bn0 + ni * 16 + l15;
      const int r0  = bm0 + mi * 16 + l4 * 4;
      float bv = 0.f;
      if (EPI == 8) bv = bias[col];
      #pragma unroll
      for (int r = 0; r < 4; ++r) {
        const size_t idx = (size_t)blockIdx.z * cstr + (size_t)(r0 + r) * ldc + col;
        const float v = acc[mi][ni][r];
        if      (EPI == 5) Ch[idx] = f2bf(v + bias[r0 + r]);
        else if (EPI == 7) Ch[idx] = f2bf(v + addf[idx]);
        else if (EPI == 8) Cf[idx] = v + bv + bf2f(addh[idx]);
      }
    }
  }
}

// ---------------------------------------------------------------------------
// LayerNorm, f32 input -> bf16 out
// ---------------------------------------------------------------------------
__global__ __launch_bounds__(256) void ln_kernel(
    const float* __restrict__ x, const float* __restrict__ g,
    const float* __restrict__ be, u16* __restrict__ out)
{
  const int row = blockIdx.x;
  const int tid = threadIdx.x;
  const float4 v = ((const float4*)(x + (size_t)row * EMBED))[tid];
  float s  = v.x + v.y + v.z + v.w;
  float s2 = v.x * v.x + v.y * v.y + v.z * v.z + v.w * v.w;
  #pragma unroll
  for (int m = 1; m < 64; m <<= 1) { s += __shfl_xor(s, m); s2 += __shfl_xor(s2, m); }
  __shared__ float ls[4], ls2[4];
  const int w = tid >> 6;
  if ((tid & 63) == 0) { ls[w] = s; ls2[w] = s2; }
  __syncthreads();
  s  = ls[0] + ls[1] + ls[2] + ls[3];
  s2 = ls2[0] + ls2[1] + ls2[2] + ls2[3];
  const float mu   = s * (1.f / EMBED);
  const float var  = s2 * (1.f / EMBED) - mu * mu;
  const float rstd = rsqrtf(var + 1e-5f);
  const float4 gv = ((const float4*)g)[tid];
  const float4 bv = ((const float4*)be)[tid];
  ushort4 o;
  o.x = f2bf((v.x - mu) * rstd * gv.x + bv.x);
  o.y = f2bf((v.y - mu) * rstd * gv.y + bv.y);
  o.z = f2bf((v.z - mu) * rstd * gv.z + bv.z);
  o.w = f2bf((v.w - mu) * rstd * gv.w + bv.w);
  ((ushort4*)(out + (size_t)row * EMBED))[tid] = o;
}

// LayerNorm, bf16 input -> bf16 out (for x2 residual path)
__global__ __launch_bounds__(256) void ln_bf16(
    const u16* __restrict__ x, const float* __restrict__ g,
    const float* __restrict__ be, u16* __restrict__ out)
{
  const int row = blockIdx.x;
  const int tid = threadIdx.x;
  const ushort4 u = ((const ushort4*)(x + (size_t)row * EMBED))[tid];
  float v0 = bf2f(u.x), v1 = bf2f(u.y), v2 = bf2f(u.z), v3 = bf2f(u.w);
  float s  = v0 + v1 + v2 + v3;
  float s2 = v0 * v0 + v1 * v1 + v2 * v2 + v3 * v3;
  #pragma unroll
  for (int m = 1; m < 64; m <<= 1) { s += __shfl_xor(s, m); s2 += __shfl_xor(s2, m); }
  __shared__ float ls[4], ls2[4];
  const int w = tid >> 6;
  if ((tid & 63) == 0) { ls[w] = s; ls2[w] = s2; }
  __syncthreads();
  s  = ls[0] + ls[1] + ls[2] + ls[3];
  s2 = ls2[0] + ls2[1] + ls2[2] + ls2[3];
  const float mu   = s * (1.f / EMBED);
  const float var  = s2 * (1.f / EMBED) - mu * mu;
  const float rstd = rsqrtf(var + 1e-5f);
  const float4 gv = ((const float4*)g)[tid];
  const float4 bv = ((const float4*)be)[tid];
  ushort4 o;
  o.x = f2bf((v0 - mu) * rstd * gv.x + bv.x);
  o.y = f2bf((v1 - mu) * rstd * gv.y + bv.y);
  o.z = f2bf((v2 - mu) * rstd * gv.z + bv.z);
  o.w = f2bf((v3 - mu) * rstd * gv.w + bv.w);
  ((ushort4*)(out + (size_t)row * EMBED))[tid] = o;
}

// ---------------------------------------------------------------------------
__global__ __launch_bounds__(256) void softmax_bf16(
    const u16* __restrict__ S, u16* __restrict__ P)
{
  const int tid = threadIdx.x;
  const size_t base = ((size_t)blockIdx.y * SEQ + blockIdx.x) * SEQ;
  const ushort4* src = (const ushort4*)(S + base);
  const ushort4 ua = src[tid];
  const ushort4 ub = src[tid + 256];
  float a0 = bf2f(ua.x), a1 = bf2f(ua.y), a2 = bf2f(ua.z), a3 = bf2f(ua.w);
  float b0 = bf2f(ub.x), b1 = bf2f(ub.y), b2 = bf2f(ub.z), b3 = bf2f(ub.w);
  float m = fmaxf(fmaxf(fmaxf(a0, a1), fmaxf(a2, a3)),
                  fmaxf(fmaxf(b0, b1), fmaxf(b2, b3)));
  #pragma unroll
  for (int msk = 1; msk < 64; msk <<= 1) m = fmaxf(m, __shfl_xor(m, msk));
  __shared__ float red[8];
  const int w = tid >> 6;
  if ((tid & 63) == 0) red[w] = m;
  __syncthreads();
  m = fmaxf(fmaxf(red[0], red[1]), fmaxf(red[2], red[3]));
  a0 = __expf(a0 - m); a1 = __expf(a1 - m); a2 = __expf(a2 - m); a3 = __expf(a3 - m);
  b0 = __expf(b0 - m); b1 = __expf(b1 - m); b2 = __expf(b2 - m); b3 = __expf(b3 - m);
  float s = a0 + a1 + a2 + a3 + b0 + b1 + b2 + b3;
  #pragma unroll
  for (int msk = 1; msk < 64; msk <<= 1) s += __shfl_xor(s, msk);
  if ((tid & 63) == 0) red[4 + w] = s;
  __syncthreads();
  s = red[4] + red[5] + red[6] + red[7];
  const float inv = 1.0f / s;
  ushort4 oa, ob;
  oa.x = f2bf(a0 * inv); oa.y = f2bf(a1 * inv); oa.z = f2bf(a2 * inv); oa.w = f2bf(a3 * inv);
  ob.x = f2bf(b0 * inv); ob.y = f2bf(b1 * inv); ob.z = f2bf(b2 * inv); ob.w = f2bf(b3 * inv);
  ushort4* dst = (ushort4*)(P + base);
  dst[tid]       = oa;
  dst[tid + 256] = ob;
}

// ---------------------------------------------------------------------------
__global__ void transpose_cast3(const float* __restrict__ W0,
                                const float* __restrict__ W1_,
                                const float* __restrict__ W2_,
                                u16* __restrict__ Wt)
{
  __shared__ float t[32][33];
  const int z = blockIdx.z;
  const float* W = (z == 0) ? W0 : (z == 1) ? W1_ : W2_;
  u16* dst = Wt + (size_t)z * EMBED * EMBED;
  const int tx = threadIdx.x, ty = threadIdx.y;
  const int n0 = blockIdx.x * 32, k0 = blockIdx.y * 32;
  #pragma unroll
  for (int i = 0; i < 4; ++i)
    t[ty + i * 8][tx] = W[(size_t)(k0 + ty + i * 8) * EMBED + n0 + tx];
  __syncthreads();
  #pragma unroll
  for (int i = 0; i < 4; ++i)
    dst[(size_t)(n0 + ty + i * 8) * EMBED + k0 + tx] = f2bf(t[tx][ty + i * 8]);
}

__global__ void transpose_cast_f32(const float* __restrict__ W, u16* __restrict__ Wt,
                                   int K, int N)
{
  __shared__ float t[32][33];
  const int tx = threadIdx.x, ty = threadIdx.y;
  const int n0 = blockIdx.x * 32, k0 = blockIdx.y * 32;
  #pragma unroll
  for (int i = 0; i < 4; ++i)
    t[ty + i * 8][tx] = W[(size_t)(k0 + ty + i * 8) * N + n0 + tx];
  __syncthreads();
  #pragma unroll
  for (int i = 0; i < 4; ++i)
    Wt[(size_t)(n0 + ty + i * 8) * K + k0 + tx] = f2bf(t[tx][ty + i * 8]);
}

__global__ void concat_bias2(const float* __restrict__ a, const float* __restrict__ b,
                             float* __restrict__ o)
{
  const int i = blockIdx.x * 1024 + threadIdx.x;
  o[i] = (i < 1024) ? a[i] : b[i - 1024];
}

// ---------------------------------------------------------------------------
extern "C" void kernel_launch(void* const* d_in, const int* in_sizes, int n_in,
                              void* d_out, int out_size, void* d_ws, size_t ws_size,
                              hipStream_t stream)
{
  const float* x   = (const float*)d_in[0];
  const float* Wq  = (const float*)d_in[1];
  const float* bq  = (const float*)d_in[2];
  const float* Wk  = (const float*)d_in[3];
  const float* bk  = (const float*)d_in[4];
  const float* Wv  = (const float*)d_in[5];
  const float* bv  = (const float*)d_in[6];
  const float* W1  = (const float*)d_in[7];
  const float* b1  = (const float*)d_in[8];
  const float* W2  = (const float*)d_in[9];
  const float* b2  = (const float*)d_in[10];
  const float* g1  = (const float*)d_in[11];
  const float* be1 = (const float*)d_in[12];
  const float* g2  = (const float*)d_in[13];
  const float* be2 = (const float*)d_in[14];
  float* out = (float*)d_out;

  const size_t RD = (size_t)NB * SEQ * EMBED;

  char* base = (char*)d_ws;
  size_t o = 0;
  auto alloc = [&](size_t bytes) -> void* {
    o = (o + 255) & ~(size_t)255;
    void* p = base + o;
    o += bytes;
    return p;
  };

  u16*   wqkv3T = (u16*)alloc((size_t)3 * EMBED * EMBED * 2);
  u16*   w1T    = (u16*)alloc((size_t)HID * EMBED * 2);
  u16*   w2T    = (u16*)alloc((size_t)EMBED * HID * 2);
  float* bqk    = (float*)alloc(2048 * 4);
  u16*   h      = (u16*)alloc(RD * 2);
  u16*   QKb    = (u16*)alloc(RD * 2 * 2);                    // [8192][2048]
  u16*   Vt     = (u16*)alloc(RD * 2);                        // [4][1024][2048]
  u16*   x2     = (u16*)alloc(RD * 2);                        // bf16 residual

  const size_t need_batched = o + (size_t)NB * SEQ * SEQ * 4 + 1024;
  const int NZ = (ws_size >= need_batched) ? NB : 1;
  u16* Sb16 = (u16*)alloc((size_t)NZ * SEQ * SEQ * 2);
  u16* Pb   = (u16*)alloc((size_t)NZ * SEQ * SEQ * 2);
  u16* ff   = (NZ == NB) ? Sb16                                // 64MB alias (S,P dead)
                         : (u16*)alloc((size_t)NB * SEQ * HID * 2);

  const u16* wqkT = wqkv3T;                                    // [2048][1024]
  const u16* wvT  = wqkv3T + (size_t)2 * EMBED * EMBED;        // [1024][1024]

  const dim3 blk(512);
  const dim3 tblk(32, 8);

  transpose_cast3<<<dim3(32, 32, 3), tblk, 0, stream>>>(Wq, Wk, Wv, wqkv3T);
  transpose_cast_f32<<<dim3(HID / 32, EMBED / 32), tblk, 0, stream>>>(W1, w1T, EMBED, HID);
  transpose_cast_f32<<<dim3(EMBED / 32, HID / 32), tblk, 0, stream>>>(W2, w2T, HID, EMBED);
  concat_bias2<<<dim3(2), dim3(1024), 0, stream>>>(bq, bk, bqk);

  ln_kernel<<<dim3(NB * SEQ), dim3(256), 0, stream>>>(x, g1, be1, h);

  // QK projection: [8192][2048]
  gemm256v3<0><<<dim3(2048 / 256, NB * SEQ / 256, 1), blk, 0, stream>>>(
      h, EMBED, 0LL, wqkT, EMBED, 0LL, QKb, 2048, 0LL, bqk, 1.f, EMBED);

  // V^T projection (direct): Vt[b][d][s] = sum_k wvT[d][k]*h[b,s,k] + bv[d]
  gemm128v3<5><<<dim3(SEQ / 128, EMBED / 256, NB), blk, 0, stream>>>(
      wvT, EMBED, 0LL, h, EMBED, (long long)SEQ * EMBED,
      Vt, SEQ, (long long)EMBED * SEQ, bv, nullptr, 1.f, EMBED);

  // attention: scores (bf16) -> softmax -> PV (+ residual -> bf16 x2)
  for (int b = 0; b < NB; b += NZ) {
    const u16* Qp  = QKb + (size_t)b * SEQ * 2048;
    const u16* Kp  = Qp + 1024;
    const u16* Vtp = Vt + (size_t)b * EMBED * SEQ;
    u16* x2p       = x2 + (size_t)b * SEQ * EMBED;
    const float* xp = x + (size_t)b * SEQ * EMBED;
    gemm256v3<6><<<dim3(SEQ / 256, SEQ / 256, NZ), blk, 0, stream>>>(
        Qp, 2048, (long long)SEQ * 2048, Kp, 2048, (long long)SEQ * 2048,
        Sb16, SEQ, (long long)SEQ * SEQ, nullptr, 0.03125f, EMBED);
    softmax_bf16<<<dim3(SEQ, NZ), dim3(256), 0, stream>>>(Sb16, Pb);
    gemm128v3<7><<<dim3(EMBED / 128, SEQ / 256, NZ), blk, 0, stream>>>(
        Pb, SEQ, (long long)SEQ * SEQ, Vtp, SEQ, (long long)EMBED * SEQ,
        x2p, EMBED, (long long)SEQ * EMBED, nullptr, xp, 1.f, SEQ);
  }

  // LN2 on bf16 residual
  ln_bf16<<<dim3(NB * SEQ), dim3(256), 0, stream>>>(x2, g2, be2, h);

  // MLP
  gemm256v3<3><<<dim3(HID / 256, NB * SEQ / 256, 1), blk, 0, stream>>>(
      h, EMBED, 0LL, w1T, EMBED, 0LL, ff, HID, 0LL, b1, 1.f, EMBED);
  gemm128v3<8><<<dim3(EMBED / 128, NB * SEQ / 256, 1), blk, 0, stream>>>(
      ff, HID, 0LL, w2T, HID, 0LL, out, EMBED, 0LL, b2, x2, 1.f, HID);
}